// Round 5
// baseline (3889.209 us; speedup 1.0000x reference)
//
#include <hip/hip_runtime.h>
#include <stdint.h>

typedef unsigned short u16;
typedef __bf16 bf16_t;
typedef bf16_t bf16x8 __attribute__((ext_vector_type(8)));
typedef float f32x4 __attribute__((ext_vector_type(4)));

// ---------- helpers ----------
__device__ __forceinline__ u16 f2b(float f) {
  union { float f; uint32_t u; } x; x.f = f;
  uint32_t r = x.u + 0x7fffu + ((x.u >> 16) & 1u);
  return (u16)(r >> 16);
}
__device__ __forceinline__ float b2f(u16 b) {
  union { uint32_t u; float f; } x; x.u = ((uint32_t)b) << 16;
  return x.f;
}

// async global->LDS, 16B per lane. LDS dest = wave-uniform base + lane*16.
__device__ __forceinline__ void async16(const void* g, void* l) {
  auto gp = reinterpret_cast<__attribute__((address_space(1))) unsigned int*>(
      reinterpret_cast<uintptr_t>(g));
  auto lp = reinterpret_cast<__attribute__((address_space(3))) unsigned int*>(
      reinterpret_cast<uintptr_t>(l));
  __builtin_amdgcn_global_load_lds(gp, lp, 16, 0, 0);
}

// ---------- generic bf16 MFMA GEMM:  C = alpha*A(MxK)*B(NxK)^T + bias [+resid] ----------
// Internals bf16; epilogue supports bf16 or f32 residual and bf16 or f32 output.
// Tile 128x128, BK=32, 256 thr (2x2 waves), XOR-swizzled LDS, global_load_lds(16B).
// M multiple of 128, K multiple of 32.
__global__ __launch_bounds__(256) void pz_gemm_bt(
    const u16* __restrict__ A, const u16* __restrict__ B,
    const float* __restrict__ bias,
    const u16* __restrict__ residB, const float* __restrict__ residF,
    u16* __restrict__ Cb, float* __restrict__ Cf,
    int M, int N, int K, int ldA, int ldB, int ldC, int ldR,
    long aSH, long bSH, long cSH, long rSH, float alpha)
{
  __shared__ __align__(16) u16 sA[128 * 32];
  __shared__ __align__(16) u16 sB[128 * 32];

  const int tid = threadIdx.x;
  const int wave = tid >> 6, lane = tid & 63;
  const int lr = lane & 15, lg = lane >> 4;
  const int wm = wave >> 1, wn = wave & 1;
  const int z = blockIdx.z;

  const u16* Ab = A + (long)z * aSH;
  const u16* Bb = B + (long)z * bSH;
  const int m0 = blockIdx.y * 128;
  const int n0 = blockIdx.x * 128;

  const int srow = tid >> 2;
  const int sgk = (tid & 3) ^ ((tid >> 3) & 3);
  int ar0 = m0 + srow;      if (ar0 > M - 1) ar0 = M - 1;
  int ar1 = m0 + 64 + srow; if (ar1 > M - 1) ar1 = M - 1;
  int br0 = n0 + srow;      if (br0 > N - 1) br0 = N - 1;
  int br1 = n0 + 64 + srow; if (br1 > N - 1) br1 = N - 1;
  const u16* aP0 = Ab + (long)ar0 * ldA + sgk * 8;
  const u16* aP1 = Ab + (long)ar1 * ldA + sgk * 8;
  const u16* bP0 = Bb + (long)br0 * ldB + sgk * 8;
  const u16* bP1 = Bb + (long)br1 * ldB + sgk * 8;
  u16* sAw0 = sA + wave * 512;
  u16* sAw1 = sA + 2048 + wave * 512;
  u16* sBw0 = sB + wave * 512;
  u16* sBw1 = sB + 2048 + wave * 512;

  const int swz = (lr >> 1) & 3;
  int aoff[4], boff[4];
#pragma unroll
  for (int i = 0; i < 4; ++i) {
    aoff[i] = (wm * 64 + i * 16 + lr) * 32 + ((lg ^ swz) * 8);
    boff[i] = (wn * 64 + i * 16 + lr) * 32 + ((lg ^ swz) * 8);
  }

  f32x4 acc[4][4] = {};
  const int kiters = K >> 5;
  for (int kt = 0; kt < kiters; ++kt) {
    const int k0 = kt << 5;
    __syncthreads();
    async16(aP0 + k0, sAw0);
    async16(aP1 + k0, sAw1);
    async16(bP0 + k0, sBw0);
    async16(bP1 + k0, sBw1);
    __builtin_amdgcn_s_waitcnt(0x0f70);  // vmcnt(0)
    __syncthreads();

    bf16x8 af[4], bfr[4];
#pragma unroll
    for (int i = 0; i < 4; ++i) af[i] = *(const bf16x8*)(sA + aoff[i]);
#pragma unroll
    for (int i = 0; i < 4; ++i) bfr[i] = *(const bf16x8*)(sB + boff[i]);
#pragma unroll
    for (int i = 0; i < 4; ++i)
#pragma unroll
      for (int j = 0; j < 4; ++j)
        acc[i][j] = __builtin_amdgcn_mfma_f32_16x16x32_bf16(af[i], bfr[j], acc[i][j], 0, 0, 0);
  }

  // C/D layout: col = lane&15, row = (lane>>4)*4 + reg  [m89/m91]
  const long coff = (long)z * cSH;
  const long roff = (long)z * rSH;
#pragma unroll
  for (int j = 0; j < 4; ++j) {
    const int n = n0 + wn * 64 + j * 16 + lr;
    if (n < N) {
      const float bv = bias ? bias[n] : 0.0f;
#pragma unroll
      for (int i = 0; i < 4; ++i) {
        const int mb = m0 + wm * 64 + i * 16 + lg * 4;
#pragma unroll
        for (int r = 0; r < 4; ++r) {
          const int m = mb + r;
          float v = alpha * acc[i][j][r] + bv;
          const long ri = roff + (long)m * ldR + n;
          if (residB) v += b2f(residB[ri]);
          if (residF) v += residF[ri];
          const long ci = coff + (long)m * ldC + n;
          if (Cb) Cb[ci] = f2b(v);
          if (Cf) Cf[ci] = v;
        }
      }
    }
  }
}

// ---------- fused dual GEMM + SwiGLU gate: G = silu(A Bu^T + bu) * (A Bv^T + bv) ----------
__global__ __launch_bounds__(256) void pz_gemm_uvgate(
    const u16* __restrict__ A, const u16* __restrict__ Bu, const u16* __restrict__ Bv,
    const float* __restrict__ biasU, const float* __restrict__ biasV,
    u16* __restrict__ G, int M, int N, int K, int ldA, int ldB, int ldG, int Npad)
{
  __shared__ __align__(16) u16 sA[128 * 32];
  __shared__ __align__(16) u16 sU[128 * 32];
  __shared__ __align__(16) u16 sV[128 * 32];

  const int tid = threadIdx.x;
  const int wave = tid >> 6, lane = tid & 63;
  const int lr = lane & 15, lg = lane >> 4;
  const int wm = wave >> 1, wn = wave & 1;
  const int m0 = blockIdx.y * 128;
  const int n0 = blockIdx.x * 128;

  const int srow = tid >> 2;
  const int sgk = (tid & 3) ^ ((tid >> 3) & 3);
  int ar0 = m0 + srow;      if (ar0 > M - 1) ar0 = M - 1;
  int ar1 = m0 + 64 + srow; if (ar1 > M - 1) ar1 = M - 1;
  int br0 = n0 + srow;      if (br0 > N - 1) br0 = N - 1;
  int br1 = n0 + 64 + srow; if (br1 > N - 1) br1 = N - 1;
  const u16* aP0 = A + (long)ar0 * ldA + sgk * 8;
  const u16* aP1 = A + (long)ar1 * ldA + sgk * 8;
  const u16* uP0 = Bu + (long)br0 * ldB + sgk * 8;
  const u16* uP1 = Bu + (long)br1 * ldB + sgk * 8;
  const u16* vP0 = Bv + (long)br0 * ldB + sgk * 8;
  const u16* vP1 = Bv + (long)br1 * ldB + sgk * 8;
  u16* sAw0 = sA + wave * 512; u16* sAw1 = sA + 2048 + wave * 512;
  u16* sUw0 = sU + wave * 512; u16* sUw1 = sU + 2048 + wave * 512;
  u16* sVw0 = sV + wave * 512; u16* sVw1 = sV + 2048 + wave * 512;

  const int swz = (lr >> 1) & 3;
  int aoff[4], boff[4];
#pragma unroll
  for (int i = 0; i < 4; ++i) {
    aoff[i] = (wm * 64 + i * 16 + lr) * 32 + ((lg ^ swz) * 8);
    boff[i] = (wn * 64 + i * 16 + lr) * 32 + ((lg ^ swz) * 8);
  }

  f32x4 aU[4][4] = {}, aV[4][4] = {};
  const int kiters = K >> 5;
  for (int kt = 0; kt < kiters; ++kt) {
    const int k0 = kt << 5;
    __syncthreads();
    async16(aP0 + k0, sAw0);
    async16(aP1 + k0, sAw1);
    async16(uP0 + k0, sUw0);
    async16(uP1 + k0, sUw1);
    async16(vP0 + k0, sVw0);
    async16(vP1 + k0, sVw1);
    __builtin_amdgcn_s_waitcnt(0x0f70);
    __syncthreads();

    bf16x8 af[4], uf[4], vf[4];
#pragma unroll
    for (int i = 0; i < 4; ++i) af[i] = *(const bf16x8*)(sA + aoff[i]);
#pragma unroll
    for (int i = 0; i < 4; ++i) uf[i] = *(const bf16x8*)(sU + boff[i]);
#pragma unroll
    for (int i = 0; i < 4; ++i) vf[i] = *(const bf16x8*)(sV + boff[i]);
#pragma unroll
    for (int i = 0; i < 4; ++i)
#pragma unroll
      for (int j = 0; j < 4; ++j) {
        aU[i][j] = __builtin_amdgcn_mfma_f32_16x16x32_bf16(af[i], uf[j], aU[i][j], 0, 0, 0);
        aV[i][j] = __builtin_amdgcn_mfma_f32_16x16x32_bf16(af[i], vf[j], aV[i][j], 0, 0, 0);
      }
  }

#pragma unroll
  for (int j = 0; j < 4; ++j) {
    const int n = n0 + wn * 64 + j * 16 + lr;
    if (n < N) {
      const float bu = biasU[n], bv = biasV[n];
#pragma unroll
      for (int i = 0; i < 4; ++i) {
        const int mb = m0 + wm * 64 + i * 16 + lg * 4;
#pragma unroll
        for (int r = 0; r < 4; ++r) {
          const float u = aU[i][j][r] + bu;
          const float v = aV[i][j][r] + bv;
          G[(long)(mb + r) * ldG + n] = f2b((u / (1.0f + __expf(-u))) * v);
        }
      }
    } else if (n < Npad) {
#pragma unroll
      for (int i = 0; i < 4; ++i) {
        const int mb = m0 + wm * 64 + i * 16 + lg * 4;
#pragma unroll
        for (int r = 0; r < 4; ++r) G[(long)(mb + r) * ldG + n] = 0;
      }
    }
  }
}

// ---------- LN over 512 (no affine; affine folded into Wqkv), f32 in, bf16 out ----------
__global__ __launch_bounds__(256) void pz_ln(const float* __restrict__ X, u16* __restrict__ O)
{
  __shared__ float sm[4], sq[4];
  const int tid = threadIdx.x;
  const long row = blockIdx.x;
  const float* x = X + row * 512;
  float a = x[tid], b = x[tid + 256];
  float s = a + b, q = a * a + b * b;
#pragma unroll
  for (int m = 32; m >= 1; m >>= 1) { s += __shfl_xor(s, m, 64); q += __shfl_xor(q, m, 64); }
  if ((tid & 63) == 0) { sm[tid >> 6] = s; sq[tid >> 6] = q; }
  __syncthreads();
  s = sm[0] + sm[1] + sm[2] + sm[3];
  q = sq[0] + sq[1] + sq[2] + sq[3];
  const float mean = s * (1.0f / 512.0f);
  const float rstd = rsqrtf(q * (1.0f / 512.0f) - mean * mean + 1e-5f);
  O[row * 512 + tid]       = f2b((a - mean) * rstd);
  O[row * 512 + tid + 256] = f2b((b - mean) * rstd);
}

// ---------- LN over concat(sctx_row[512] bf16, tmean_b[512] f32) -> h bf16 (1024) ----------
__global__ __launch_bounds__(256) void pz_mix_ln(
    const u16* __restrict__ SC, const float* __restrict__ TM,
    const float* __restrict__ g, const float* __restrict__ b, u16* __restrict__ H)
{
  __shared__ float sm[4], sq[4];
  const int tid = threadIdx.x;
  const long row = blockIdx.x;
  const int bb = (int)(row >> 12);
  const u16* x0 = SC + row * 512;
  const float* x1 = TM + (long)bb * 512;
  float v0 = b2f(x0[tid]), v1 = b2f(x0[tid + 256]);
  float v2 = x1[tid], v3 = x1[tid + 256];
  float s = v0 + v1 + v2 + v3;
  float q = v0 * v0 + v1 * v1 + v2 * v2 + v3 * v3;
#pragma unroll
  for (int m = 32; m >= 1; m >>= 1) { s += __shfl_xor(s, m, 64); q += __shfl_xor(q, m, 64); }
  if ((tid & 63) == 0) { sm[tid >> 6] = s; sq[tid >> 6] = q; }
  __syncthreads();
  s = sm[0] + sm[1] + sm[2] + sm[3];
  q = sq[0] + sq[1] + sq[2] + sq[3];
  const float mean = s * (1.0f / 1024.0f);
  const float rstd = rsqrtf(q * (1.0f / 1024.0f) - mean * mean + 1e-5f);
  u16* hr = H + row * 1024;
  hr[tid]       = f2b((v0 - mean) * rstd * g[tid]       + b[tid]);
  hr[tid + 256] = f2b((v1 - mean) * rstd * g[tid + 256] + b[tid + 256]);
  hr[tid + 512] = f2b((v2 - mean) * rstd * g[tid + 512] + b[tid + 512]);
  hr[tid + 768] = f2b((v3 - mean) * rstd * g[tid + 768] + b[tid + 768]);
}

// ---------- in-place row softmax on bf16 scores ----------
template <int L>
__global__ __launch_bounds__(256) void pz_softmax(u16* __restrict__ S)
{
  __shared__ float sm[4], ss[4];
  const int tid = threadIdx.x;
  const long row = blockIdx.x;
  u16* p = S + row * (long)L;
  constexpr int per = L >> 8;
  float v[per];
  float mx = -3.0e38f;
#pragma unroll
  for (int i = 0; i < per; ++i) { v[i] = b2f(p[tid + (i << 8)]); mx = fmaxf(mx, v[i]); }
#pragma unroll
  for (int m = 32; m >= 1; m >>= 1) mx = fmaxf(mx, __shfl_xor(mx, m, 64));
  if ((tid & 63) == 0) sm[tid >> 6] = mx;
  __syncthreads();
  mx = fmaxf(fmaxf(sm[0], sm[1]), fmaxf(sm[2], sm[3]));
  float s = 0.0f;
#pragma unroll
  for (int i = 0; i < per; ++i) { v[i] = __expf(v[i] - mx); s += v[i]; }
#pragma unroll
  for (int m = 32; m >= 1; m >>= 1) s += __shfl_xor(s, m, 64);
  if ((tid & 63) == 0) ss[tid >> 6] = s;
  __syncthreads();
  const float inv = 1.0f / (ss[0] + ss[1] + ss[2] + ss[3]);
#pragma unroll
  for (int i = 0; i < per; ++i) p[tid + (i << 8)] = f2b(v[i] * inv);
}

// ---------- bf16 slice transpose: D[(z*64+d)*Nk + nk] = S[nk*ldS + colBase + z*64 + d] ----------
__global__ __launch_bounds__(256) void pz_transpose(
    const u16* __restrict__ S, u16* __restrict__ D, int Nk, int ldS, int colBase)
{
  __shared__ u16 t[64][65];
  const int z = blockIdx.z;
  const int nk0 = blockIdx.x * 64;
  const int tid = threadIdx.x;
  for (int i = tid; i < 4096; i += 256) {
    int r = i >> 6, d = i & 63;
    t[r][d] = S[(long)(nk0 + r) * ldS + colBase + z * 64 + d];
  }
  __syncthreads();
  for (int i = tid; i < 4096; i += 256) {
    int d = i >> 6, c = i & 63;
    D[((long)z * 64 + d) * Nk + nk0 + c] = t[c][d];
  }
}

// ---------- f32 transpose + convert to bf16 (for Wo^T) ----------
__global__ __launch_bounds__(256) void pz_transpose_f2b(
    const float* __restrict__ S, u16* __restrict__ D, int Nk, int ldS)
{
  __shared__ u16 t[64][65];
  const int z = blockIdx.z;
  const int nk0 = blockIdx.x * 64;
  const int tid = threadIdx.x;
  for (int i = tid; i < 4096; i += 256) {
    int r = i >> 6, d = i & 63;
    t[r][d] = f2b(S[(long)(nk0 + r) * ldS + z * 64 + d]);
  }
  __syncthreads();
  for (int i = tid; i < 4096; i += 256) {
    int d = i >> 6, c = i & 63;
    D[((long)z * 64 + d) * Nk + nk0 + c] = t[c][d];
  }
}

// ---------- f32 -> bf16 flat convert ----------
__global__ __launch_bounds__(256) void pz_f2b(const float* __restrict__ s, u16* __restrict__ d, int n)
{
  int i = blockIdx.x * 256 + threadIdx.x;
  if (i < n) d[i] = f2b(s[i]);
}

// ---------- fold LN affine into Wqkv: W' = bf16(W*g(col)), b' = bqkv + W.b_ln (f32 in) ----------
__global__ __launch_bounds__(256) void pz_fold_qkv(
    const float* __restrict__ Ws, const float* __restrict__ Wt,
    const float* __restrict__ bs, const float* __restrict__ bt,
    const float* s_qg, const float* s_qb, const float* s_kg, const float* s_kb,
    const float* t_qg, const float* t_qb, const float* t_kg, const float* t_kb,
    u16* __restrict__ Wps, u16* __restrict__ Wpt, float* bps, float* bpt)
{
  __shared__ float sb[4];
  const int id = blockIdx.x;
  const int mat = (id >= 1536) ? 1 : 0;
  const int r = id - mat * 1536;
  const float* W = mat ? Wt : Ws;
  const float* bq = mat ? bt : bs;
  const float *g, *bl;
  if (!mat) { g = (r < 512) ? s_qg : s_kg; bl = (r < 512) ? s_qb : s_kb; }
  else      { g = (r < 512) ? t_qg : t_kg; bl = (r < 512) ? t_qb : t_kb; }
  u16* Wo_ = mat ? Wpt : Wps;
  float* bo_ = mat ? bpt : bps;
  float dot = 0.0f;
  for (int c = threadIdx.x; c < 512; c += 256) {
    float w = W[(long)r * 512 + c];
    Wo_[(long)r * 512 + c] = f2b(w * g[c]);
    dot += w * bl[c];
  }
#pragma unroll
  for (int m = 32; m >= 1; m >>= 1) dot += __shfl_xor(dot, m, 64);
  if ((threadIdx.x & 63) == 0) sb[threadIdx.x >> 6] = dot;
  __syncthreads();
  if (threadIdx.x == 0) bo_[r] = sb[0] + sb[1] + sb[2] + sb[3] + bq[r];
}

// ---------- combined proj bias: bc = Wp . bo + bp (f32) ----------
__global__ __launch_bounds__(256) void pz_fold_bc(
    const float* Wps_, const float* bos, const float* bps_,
    const float* Wpt_, const float* bot, const float* bpt_, float* bcs, float* bct)
{
  __shared__ float sb[4];
  const int id = blockIdx.x;
  const int mat = id >> 9, i = id & 511;
  const float* W = mat ? Wpt_ : Wps_;
  const float* bo = mat ? bot : bos;
  const float* bp = mat ? bpt_ : bps_;
  float* o = mat ? bct : bcs;
  float dot = 0.0f;
  for (int j = threadIdx.x; j < 512; j += 256) dot += W[(long)i * 512 + j] * bo[j];
#pragma unroll
  for (int m = 32; m >= 1; m >>= 1) dot += __shfl_xor(dot, m, 64);
  if ((threadIdx.x & 63) == 0) sb[threadIdx.x >> 6] = dot;
  __syncthreads();
  if (threadIdx.x == 0) o[i] = sb[0] + sb[1] + sb[2] + sb[3] + bp[i];
}

// ---------- Wout zero-pad 2730 -> 2752 cols (f32 -> bf16) ----------
__global__ __launch_bounds__(256) void pz_pad_wout(const float* __restrict__ W, u16* __restrict__ D)
{
  const int idx = blockIdx.x * 256 + threadIdx.x;  // grid covers 512*2752 exactly
  const int r = idx / 2752, c = idx - r * 2752;
  D[idx] = (c < 2730) ? f2b(W[(long)r * 2730 + c]) : (u16)0;
}

// ---------- t_ctx mean over tokens (tctx bf16; O f32 must be zeroed) ----------
__global__ __launch_bounds__(256) void pz_tmean(const u16* __restrict__ T, float* __restrict__ O)
{
  const int b = blockIdx.y, tc = blockIdx.x, tid = threadIdx.x;
  const u16* base = T + (long)b * 512 * 512 + (long)tc * 32 * 512;
  float s0 = 0.0f, s1 = 0.0f;
#pragma unroll 4
  for (int t = 0; t < 32; ++t) { s0 += b2f(base[t * 512 + tid]); s1 += b2f(base[t * 512 + tid + 256]); }
  atomicAdd(&O[b * 512 + tid],       s0 * (1.0f / 512.0f));
  atomicAdd(&O[b * 512 + tid + 256], s1 * (1.0f / 512.0f));
}

// ---------- diagnostic fill (reports ws_size in MB via absmax if ws too small) ----------
__global__ void pz_diag(float* __restrict__ out, long n, float val)
{
  for (long i = (long)blockIdx.x * 256 + threadIdx.x; i < n; i += (long)gridDim.x * 256)
    out[i] = val;
}

// ---------- host ----------
extern "C" void kernel_launch(void* const* d_in, const int* in_sizes, int n_in,
                              void* d_out, int out_size, void* d_ws, size_t ws_size,
                              hipStream_t stream)
{
  (void)in_sizes; (void)n_in;
  const float* spat   = (const float*)d_in[0];
  const float* temp   = (const float*)d_in[1];
  const float* s_qg = (const float*)d_in[2],  * s_qb = (const float*)d_in[3];
  const float* s_kg = (const float*)d_in[4],  * s_kb = (const float*)d_in[5];
  const float* s_Wqkv = (const float*)d_in[6], * s_bqkv = (const float*)d_in[7];
  const float* s_Wo = (const float*)d_in[8],  * s_bo = (const float*)d_in[9];
  const float* s_Wp = (const float*)d_in[10], * s_bp = (const float*)d_in[11];
  const float* t_qg = (const float*)d_in[12], * t_qb = (const float*)d_in[13];
  const float* t_kg = (const float*)d_in[14], * t_kb = (const float*)d_in[15];
  const float* t_Wqkv = (const float*)d_in[16], * t_bqkv = (const float*)d_in[17];
  const float* t_Wo = (const float*)d_in[18], * t_bo = (const float*)d_in[19];
  const float* t_Wp = (const float*)d_in[20], * t_bp = (const float*)d_in[21];
  const float* mix_g = (const float*)d_in[22], * mix_b = (const float*)d_in[23];
  const float* mix_Win = (const float*)d_in[24], * mix_bin = (const float*)d_in[25];
  const float* mix_Wout = (const float*)d_in[26], * mix_bout = (const float*)d_in[27];
  float* out = (float*)d_out;

  char* ws = (char*)d_ws;
  size_t off = 0;
  auto take = [&](size_t n) { void* p = ws + off; off += (n + 255) & ~(size_t)255; return p; };

  u16* wq_s  = (u16*)take(1536L * 512 * 2);   // folded s_Wqkv' (bf16)
  u16* wq_t  = (u16*)take(1536L * 512 * 2);
  u16* wc_s  = (u16*)take(512L * 512 * 2);    // Wp.Wo combined (bf16)
  u16* wc_t  = (u16*)take(512L * 512 * 2);
  u16* woutp = (u16*)take(512L * 2752 * 2);   // Wout zero-padded (bf16)
  float* bqs = (float*)take(1536L * 4);
  float* bqt = (float*)take(1536L * 4);
  float* bcs = (float*)take(512L * 4);
  float* bct = (float*)take(512L * 4);
  // A region: nhat -> later ctx
  u16* nhat_s = (u16*)take(16384L * 512 * 2);   // -> ctx_s
  u16* nhat_t = (u16*)take(2048L * 512 * 2);    // -> ctx_t
  // B region: qkv -> later sctx/tctx/tmean/hbuf
  u16* q_s  = (u16*)take(16384L * 512 * 2);     // -> sctx (bf16)
  u16* kv_s = (u16*)take(2048L * 1024 * 2);     // -> tctx (bf16)
  u16* q_t  = (u16*)take(2048L * 512 * 2);      // -> tmean (f32, 8KB)
  u16* kv_t = (u16*)take(16384L * 1024 * 2);    // -> hbuf (bf16)
  // S region: precompute scratch (wtT|wpb) -> Sb|vt_s|vtc -> gchunk|winb
  char* Sreg = (char*)take(16777216 + 2097152 + 4194304);
  const size_t NEED = off;

  if (ws_size < NEED) {  // diagnostic: absmax will report ws budget in MB
    pz_diag<<<2048, 256, 0, stream>>>(out, (long)out_size, (float)(ws_size >> 20));
    return;
  }

  u16* wtT  = (u16*)Sreg;                    // 0.5MB precompute scratch
  u16* wpb  = (u16*)(Sreg + 524288);         // 0.5MB precompute scratch
  u16* Sb   = (u16*)Sreg;
  u16* vt_s = (u16*)(Sreg + 16777216);
  u16* vtc  = (u16*)(Sreg + 16777216 + 2097152);
  u16* ctx_s = nhat_s;
  u16* ctx_t = nhat_t;
  u16* sctx  = q_s;
  u16* tctx  = kv_s;
  float* tmean = (float*)q_t;
  u16* hbuf  = kv_t;
  // mix phase (attention done, Sreg free): gchunk 2048*2752*2=11.27MB, winb 11.18MB
  u16* gchunk = (u16*)Sreg;
  u16* winb   = (u16*)(Sreg + 11272192);     // 11272192+11182080 = 22.45MB <= 23.07MB

  auto gemm = [&](const u16* A, const u16* B, const float* bias,
                  const u16* residB, const float* residF, u16* Cb, float* Cf,
                  int M, int N, int K, int ldA, int ldB, int ldC, int ldR,
                  long aSH, long bSH, long cSH, long rSH, int Z, float alpha) {
    dim3 g((N + 127) / 128, M / 128, Z);
    pz_gemm_bt<<<g, dim3(256), 0, stream>>>(A, B, bias, residB, residF, Cb, Cf,
        M, N, K, ldA, ldB, ldC, ldR, aSH, bSH, cSH, rSH, alpha);
  };

  // --- precompute: fold LN->Wqkv, Wc = Wp.Wo (bf16 GEMM), Wout pad, biases ---
  pz_fold_qkv<<<3072, 256, 0, stream>>>(s_Wqkv, t_Wqkv, s_bqkv, t_bqkv,
      s_qg, s_qb, s_kg, s_kb, t_qg, t_qb, t_kg, t_kb, wq_s, wq_t, bqs, bqt);
  pz_transpose_f2b<<<dim3(8, 1, 8), 256, 0, stream>>>(s_Wo, wtT, 512, 512);
  pz_f2b<<<1024, 256, 0, stream>>>(s_Wp, wpb, 512 * 512);
  gemm(wpb, wtT, nullptr, nullptr, nullptr, wc_s, nullptr,
       512, 512, 512, 512, 512, 512, 0, 0, 0, 0, 0, 1, 1.0f);
  pz_transpose_f2b<<<dim3(8, 1, 8), 256, 0, stream>>>(t_Wo, wtT, 512, 512);
  pz_f2b<<<1024, 256, 0, stream>>>(t_Wp, wpb, 512 * 512);
  gemm(wpb, wtT, nullptr, nullptr, nullptr, wc_t, nullptr,
       512, 512, 512, 512, 512, 512, 0, 0, 0, 0, 0, 1, 1.0f);
  pz_fold_bc<<<1024, 256, 0, stream>>>(s_Wp, s_bo, s_bp, t_Wp, t_bo, t_bp, bcs, bct);
  pz_pad_wout<<<5504, 256, 0, stream>>>(mix_Wout, woutp);

  // --- LN (normalized only; affine folded) ---
  pz_ln<<<16384, 256, 0, stream>>>(spat, nhat_s);
  pz_ln<<<2048, 256, 0, stream>>>(temp, nhat_t);

  // --- QKV projections ---
  gemm(nhat_s, wq_s,           bqs,       nullptr, nullptr, q_s,  nullptr,
       16384, 512,  512, 512, 512, 512,  0, 0,0,0,0, 1, 1.0f);
  gemm(nhat_t, wq_s + 512*512, bqs + 512, nullptr, nullptr, kv_s, nullptr,
       2048,  1024, 512, 512, 512, 1024, 0, 0,0,0,0, 1, 1.0f);
  gemm(nhat_t, wq_t,           bqt,       nullptr, nullptr, q_t,  nullptr,
       2048,  512,  512, 512, 512, 512,  0, 0,0,0,0, 1, 1.0f);
  gemm(nhat_s, wq_t + 512*512, bqt + 512, nullptr, nullptr, kv_t, nullptr,
       16384, 1024, 512, 512, 512, 1024, 0, 0,0,0,0, 1, 1.0f);

  // --- spatial-query attention (chunk: batch x 4 heads; S chunk = 16MB) ---
  for (int b = 0; b < 4; ++b)
    pz_transpose<<<dim3(8, 1, 8), 256, 0, stream>>>(kv_s + (long)b * 512 * 1024,
        vt_s + (long)b * 8 * 64 * 512, 512, 1024, 512);
  for (int b = 0; b < 4; ++b)
    for (int hc = 0; hc < 2; ++hc) {
      const u16* Aq = q_s + (long)b * 4096 * 512 + hc * 256;
      const u16* Bk = kv_s + (long)b * 512 * 1024 + hc * 256;
      gemm(Aq, Bk, nullptr, nullptr, nullptr, Sb, nullptr,
           4096, 512, 64, 512, 1024, 512, 0, 64, 64, 4096L * 512, 0, 4, 0.125f);
      pz_softmax<512><<<16384, 256, 0, stream>>>(Sb);
      const u16* Bv = vt_s + ((long)b * 8 + hc * 4) * 64 * 512;
      gemm(Sb, Bv, nullptr, nullptr, nullptr, ctx_s + (long)b * 4096 * 512 + hc * 256, nullptr,
           4096, 64, 512, 512, 512, 512, 0, 4096L * 512, 64L * 512, 64, 0, 4, 1.0f);
    }

  // --- temporal-query attention (chunk: batch x head-pair; S chunk = 8MB) ---
  for (int b = 0; b < 4; ++b) {
    const u16* Bk = kv_t + (long)b * 4096 * 1024;
    pz_transpose<<<dim3(64, 1, 8), 256, 0, stream>>>(Bk, vtc, 4096, 1024, 512);
    for (int hp = 0; hp < 4; ++hp) {
      const u16* Aq = q_t + (long)b * 512 * 512 + hp * 128;
      gemm(Aq, Bk + hp * 128, nullptr, nullptr, nullptr, Sb, nullptr,
           512, 4096, 64, 512, 1024, 4096, 0, 64, 64, 512L * 4096, 0, 2, 0.125f);
      pz_softmax<4096><<<1024, 256, 0, stream>>>(Sb);
      gemm(Sb, vtc + (long)hp * 2 * 64 * 4096, nullptr, nullptr, nullptr,
           ctx_t + (long)b * 512 * 512 + hp * 128, nullptr,
           512, 64, 4096, 4096, 4096, 512, 0, 512L * 4096, 64L * 4096, 64, 0, 2, 1.0f);
    }
  }

  // --- combined output projection (Wc = Wp.Wo) + f32 residual -> bf16 ctx ---
  gemm(ctx_s, wc_s, bcs, nullptr, spat, sctx, nullptr,
       16384, 512, 512, 512, 512, 512, 512, 0,0,0,0, 1, 1.0f);
  gemm(ctx_t, wc_t, bct, nullptr, temp, tctx, nullptr,
       2048,  512, 512, 512, 512, 512, 512, 0,0,0,0, 1, 1.0f);

  // --- t_mean + mix LN ---
  (void)hipMemsetAsync(tmean, 0, 4L * 512 * sizeof(float), stream);
  pz_tmean<<<dim3(16, 4), 256, 0, stream>>>(tctx, tmean);
  pz_mix_ln<<<16384, 256, 0, stream>>>(sctx, tmean, mix_g, mix_b, hbuf);

  // --- mix_Win -> bf16 (Sreg free now; winb behind gchunk) ---
  pz_f2b<<<21840, 256, 0, stream>>>(mix_Win, winb, 5460 * 1024);

  // --- mix MLP in 8 row-chunks of 2048: fused u/v+gate GEMM, then Wout GEMM + resid ---
  for (int c = 0; c < 8; ++c) {
    const u16* Ah = hbuf + (long)c * 2048 * 1024;
    pz_gemm_uvgate<<<dim3(22, 16), 256, 0, stream>>>(Ah, winb, winb + 2730L * 1024,
        mix_bin, mix_bin + 2730, gchunk, 2048, 2730, 1024, 1024, 1024, 2752, 2752);
    gemm(gchunk, woutp, mix_bout, sctx + (long)c * 2048 * 512, nullptr,
         nullptr, out + (long)c * 2048 * 512,
         2048, 512, 2752, 2752, 2752, 512, 512, 0,0,0,0, 1, 1.0f);
  }
}

// Round 6
// 2661.543 us; speedup vs baseline: 1.4613x; 1.4613x over previous
//
#include <hip/hip_runtime.h>
#include <stdint.h>

typedef unsigned short u16;
typedef __bf16 bf16_t;
typedef bf16_t bf16x8 __attribute__((ext_vector_type(8)));
typedef float f32x4 __attribute__((ext_vector_type(4)));

// ---------- helpers ----------
__device__ __forceinline__ u16 f2b(float f) {
  union { float f; uint32_t u; } x; x.f = f;
  uint32_t r = x.u + 0x7fffu + ((x.u >> 16) & 1u);
  return (u16)(r >> 16);
}
__device__ __forceinline__ float b2f(u16 b) {
  union { uint32_t u; float f; } x; x.u = ((uint32_t)b) << 16;
  return x.f;
}

// async global->LDS, 16B per lane. LDS dest = wave-uniform base + lane*16.
__device__ __forceinline__ void async16(const void* g, void* l) {
  auto gp = reinterpret_cast<__attribute__((address_space(1))) unsigned int*>(
      reinterpret_cast<uintptr_t>(g));
  auto lp = reinterpret_cast<__attribute__((address_space(3))) unsigned int*>(
      reinterpret_cast<uintptr_t>(l));
  __builtin_amdgcn_global_load_lds(gp, lp, 16, 0, 0);
}

// ---------- generic bf16 MFMA GEMM:  C = alpha*A(MxK)*B(NxK)^T + bias [+resid] ----------
__global__ __launch_bounds__(256) void pz_gemm_bt(
    const u16* __restrict__ A, const u16* __restrict__ B,
    const float* __restrict__ bias,
    const u16* __restrict__ residB, const float* __restrict__ residF,
    u16* __restrict__ Cb, float* __restrict__ Cf,
    int M, int N, int K, int ldA, int ldB, int ldC, int ldR,
    long aSH, long bSH, long cSH, long rSH, float alpha)
{
  __shared__ __align__(16) u16 sA[128 * 32];
  __shared__ __align__(16) u16 sB[128 * 32];

  const int tid = threadIdx.x;
  const int wave = tid >> 6, lane = tid & 63;
  const int lr = lane & 15, lg = lane >> 4;
  const int wm = wave >> 1, wn = wave & 1;
  const int z = blockIdx.z;

  const u16* Ab = A + (long)z * aSH;
  const u16* Bb = B + (long)z * bSH;
  const int m0 = blockIdx.y * 128;
  const int n0 = blockIdx.x * 128;

  const int srow = tid >> 2;
  const int sgk = (tid & 3) ^ ((tid >> 3) & 3);
  int ar0 = m0 + srow;      if (ar0 > M - 1) ar0 = M - 1;
  int ar1 = m0 + 64 + srow; if (ar1 > M - 1) ar1 = M - 1;
  int br0 = n0 + srow;      if (br0 > N - 1) br0 = N - 1;
  int br1 = n0 + 64 + srow; if (br1 > N - 1) br1 = N - 1;
  const u16* aP0 = Ab + (long)ar0 * ldA + sgk * 8;
  const u16* aP1 = Ab + (long)ar1 * ldA + sgk * 8;
  const u16* bP0 = Bb + (long)br0 * ldB + sgk * 8;
  const u16* bP1 = Bb + (long)br1 * ldB + sgk * 8;
  u16* sAw0 = sA + wave * 512;
  u16* sAw1 = sA + 2048 + wave * 512;
  u16* sBw0 = sB + wave * 512;
  u16* sBw1 = sB + 2048 + wave * 512;

  const int swz = (lr >> 1) & 3;
  int aoff[4], boff[4];
#pragma unroll
  for (int i = 0; i < 4; ++i) {
    aoff[i] = (wm * 64 + i * 16 + lr) * 32 + ((lg ^ swz) * 8);
    boff[i] = (wn * 64 + i * 16 + lr) * 32 + ((lg ^ swz) * 8);
  }

  f32x4 acc[4][4] = {};
  const int kiters = K >> 5;
  for (int kt = 0; kt < kiters; ++kt) {
    const int k0 = kt << 5;
    __syncthreads();
    async16(aP0 + k0, sAw0);
    async16(aP1 + k0, sAw1);
    async16(bP0 + k0, sBw0);
    async16(bP1 + k0, sBw1);
    __builtin_amdgcn_s_waitcnt(0x0f70);  // vmcnt(0)
    __syncthreads();

    bf16x8 af[4], bfr[4];
#pragma unroll
    for (int i = 0; i < 4; ++i) af[i] = *(const bf16x8*)(sA + aoff[i]);
#pragma unroll
    for (int i = 0; i < 4; ++i) bfr[i] = *(const bf16x8*)(sB + boff[i]);
#pragma unroll
    for (int i = 0; i < 4; ++i)
#pragma unroll
      for (int j = 0; j < 4; ++j)
        acc[i][j] = __builtin_amdgcn_mfma_f32_16x16x32_bf16(af[i], bfr[j], acc[i][j], 0, 0, 0);
  }

  // C/D layout: col = lane&15, row = (lane>>4)*4 + reg  [m89/m91]
  const long coff = (long)z * cSH;
  const long roff = (long)z * rSH;
#pragma unroll
  for (int j = 0; j < 4; ++j) {
    const int n = n0 + wn * 64 + j * 16 + lr;
    if (n < N) {
      const float bv = bias ? bias[n] : 0.0f;
#pragma unroll
      for (int i = 0; i < 4; ++i) {
        const int mb = m0 + wm * 64 + i * 16 + lg * 4;
#pragma unroll
        for (int r = 0; r < 4; ++r) {
          const int m = mb + r;
          float v = alpha * acc[i][j][r] + bv;
          const long ri = roff + (long)m * ldR + n;
          if (residB) v += b2f(residB[ri]);
          if (residF) v += residF[ri];
          const long ci = coff + (long)m * ldC + n;
          if (Cb) Cb[ci] = f2b(v);
          if (Cf) Cf[ci] = v;
        }
      }
    }
  }
}

// ---------- split-K P.V GEMM: C(Mx64) += A(MxK).B(64xK)^T, f32 atomic out ----------
// Tile 128x64 (2x2 waves, acc[4][2]); blockIdx.x = K-split (kchunk each); z-batched.
// C must be zeroed before. M multiple of 128, kchunk multiple of 32.
__global__ __launch_bounds__(256) void pz_gemm_pv(
    const u16* __restrict__ A, const u16* __restrict__ B, float* __restrict__ C,
    int M, int ldA, int ldB, long aSH, long bSH, long cSH, int kchunk)
{
  __shared__ __align__(16) u16 sA[128 * 32];
  __shared__ __align__(16) u16 sB[64 * 32];

  const int tid = threadIdx.x;
  const int wave = tid >> 6, lane = tid & 63;
  const int lr = lane & 15, lg = lane >> 4;
  const int wm = wave >> 1, wn = wave & 1;
  const int z = blockIdx.z;
  const int m0 = blockIdx.y * 128;
  const int kbase = blockIdx.x * kchunk;

  const u16* Ab = A + (long)z * aSH;
  const u16* Bb = B + (long)z * bSH;

  const int srow = tid >> 2;                       // 0..63
  const int sgk = (tid & 3) ^ ((tid >> 3) & 3);
  const u16* aP0 = Ab + (long)(m0 + srow) * ldA + sgk * 8;
  const u16* aP1 = Ab + (long)(m0 + 64 + srow) * ldA + sgk * 8;
  const u16* bP  = Bb + (long)srow * ldB + sgk * 8;
  u16* sAw0 = sA + wave * 512;
  u16* sAw1 = sA + 2048 + wave * 512;
  u16* sBw  = sB + wave * 512;

  const int swz = (lr >> 1) & 3;
  int aoff[4], boff[2];
#pragma unroll
  for (int i = 0; i < 4; ++i) aoff[i] = (wm * 64 + i * 16 + lr) * 32 + ((lg ^ swz) * 8);
#pragma unroll
  for (int j = 0; j < 2; ++j) boff[j] = (wn * 32 + j * 16 + lr) * 32 + ((lg ^ swz) * 8);

  f32x4 acc[4][2] = {};
  const int kiters = kchunk >> 5;
  for (int kt = 0; kt < kiters; ++kt) {
    const int k0 = kbase + (kt << 5);
    __syncthreads();
    async16(aP0 + k0, sAw0);
    async16(aP1 + k0, sAw1);
    async16(bP  + k0, sBw);
    __builtin_amdgcn_s_waitcnt(0x0f70);  // vmcnt(0)
    __syncthreads();

    bf16x8 af[4], bfr[2];
#pragma unroll
    for (int i = 0; i < 4; ++i) af[i] = *(const bf16x8*)(sA + aoff[i]);
#pragma unroll
    for (int j = 0; j < 2; ++j) bfr[j] = *(const bf16x8*)(sB + boff[j]);
#pragma unroll
    for (int i = 0; i < 4; ++i)
#pragma unroll
      for (int j = 0; j < 2; ++j)
        acc[i][j] = __builtin_amdgcn_mfma_f32_16x16x32_bf16(af[i], bfr[j], acc[i][j], 0, 0, 0);
  }

  const long coff = (long)z * cSH;
#pragma unroll
  for (int j = 0; j < 2; ++j) {
    const int n = wn * 32 + j * 16 + lr;
#pragma unroll
    for (int i = 0; i < 4; ++i) {
      const int mb = m0 + wm * 64 + i * 16 + lg * 4;
#pragma unroll
      for (int r = 0; r < 4; ++r)
        atomicAdd(&C[coff + (long)(mb + r) * 64 + n], acc[i][j][r]);
    }
  }
}

// ---------- P.V finalize: f32 [z][M][64] -> bf16 dst[m*ldD + z*64 + d] ----------
__global__ __launch_bounds__(256) void pz_pv_fin(
    const float* __restrict__ S, u16* __restrict__ D, int M, int ldD)
{
  const long idx = (long)blockIdx.x * 256 + threadIdx.x;  // grid covers Z*M*64
  const int d = (int)(idx & 63);
  const long rem = idx >> 6;
  const int m = (int)(rem % M);
  const int z = (int)(rem / M);
  D[(long)m * ldD + z * 64 + d] = f2b(S[idx]);
}

// ---------- fused dual GEMM + SwiGLU gate: G = silu(A Bu^T + bu) * (A Bv^T + bv) ----------
__global__ __launch_bounds__(256) void pz_gemm_uvgate(
    const u16* __restrict__ A, const u16* __restrict__ Bu, const u16* __restrict__ Bv,
    const float* __restrict__ biasU, const float* __restrict__ biasV,
    u16* __restrict__ G, int M, int N, int K, int ldA, int ldB, int ldG, int Npad)
{
  __shared__ __align__(16) u16 sA[128 * 32];
  __shared__ __align__(16) u16 sU[128 * 32];
  __shared__ __align__(16) u16 sV[128 * 32];

  const int tid = threadIdx.x;
  const int wave = tid >> 6, lane = tid & 63;
  const int lr = lane & 15, lg = lane >> 4;
  const int wm = wave >> 1, wn = wave & 1;
  const int m0 = blockIdx.y * 128;
  const int n0 = blockIdx.x * 128;

  const int srow = tid >> 2;
  const int sgk = (tid & 3) ^ ((tid >> 3) & 3);
  int ar0 = m0 + srow;      if (ar0 > M - 1) ar0 = M - 1;
  int ar1 = m0 + 64 + srow; if (ar1 > M - 1) ar1 = M - 1;
  int br0 = n0 + srow;      if (br0 > N - 1) br0 = N - 1;
  int br1 = n0 + 64 + srow; if (br1 > N - 1) br1 = N - 1;
  const u16* aP0 = A + (long)ar0 * ldA + sgk * 8;
  const u16* aP1 = A + (long)ar1 * ldA + sgk * 8;
  const u16* uP0 = Bu + (long)br0 * ldB + sgk * 8;
  const u16* uP1 = Bu + (long)br1 * ldB + sgk * 8;
  const u16* vP0 = Bv + (long)br0 * ldB + sgk * 8;
  const u16* vP1 = Bv + (long)br1 * ldB + sgk * 8;
  u16* sAw0 = sA + wave * 512; u16* sAw1 = sA + 2048 + wave * 512;
  u16* sUw0 = sU + wave * 512; u16* sUw1 = sU + 2048 + wave * 512;
  u16* sVw0 = sV + wave * 512; u16* sVw1 = sV + 2048 + wave * 512;

  const int swz = (lr >> 1) & 3;
  int aoff[4], boff[4];
#pragma unroll
  for (int i = 0; i < 4; ++i) {
    aoff[i] = (wm * 64 + i * 16 + lr) * 32 + ((lg ^ swz) * 8);
    boff[i] = (wn * 64 + i * 16 + lr) * 32 + ((lg ^ swz) * 8);
  }

  f32x4 aU[4][4] = {}, aV[4][4] = {};
  const int kiters = K >> 5;
  for (int kt = 0; kt < kiters; ++kt) {
    const int k0 = kt << 5;
    __syncthreads();
    async16(aP0 + k0, sAw0);
    async16(aP1 + k0, sAw1);
    async16(uP0 + k0, sUw0);
    async16(uP1 + k0, sUw1);
    async16(vP0 + k0, sVw0);
    async16(vP1 + k0, sVw1);
    __builtin_amdgcn_s_waitcnt(0x0f70);
    __syncthreads();

    bf16x8 af[4], uf[4], vf[4];
#pragma unroll
    for (int i = 0; i < 4; ++i) af[i] = *(const bf16x8*)(sA + aoff[i]);
#pragma unroll
    for (int i = 0; i < 4; ++i) uf[i] = *(const bf16x8*)(sU + boff[i]);
#pragma unroll
    for (int i = 0; i < 4; ++i) vf[i] = *(const bf16x8*)(sV + boff[i]);
#pragma unroll
    for (int i = 0; i < 4; ++i)
#pragma unroll
      for (int j = 0; j < 4; ++j) {
        aU[i][j] = __builtin_amdgcn_mfma_f32_16x16x32_bf16(af[i], uf[j], aU[i][j], 0, 0, 0);
        aV[i][j] = __builtin_amdgcn_mfma_f32_16x16x32_bf16(af[i], vf[j], aV[i][j], 0, 0, 0);
      }
  }

#pragma unroll
  for (int j = 0; j < 4; ++j) {
    const int n = n0 + wn * 64 + j * 16 + lr;
    if (n < N) {
      const float bu = biasU[n], bv = biasV[n];
#pragma unroll
      for (int i = 0; i < 4; ++i) {
        const int mb = m0 + wm * 64 + i * 16 + lg * 4;
#pragma unroll
        for (int r = 0; r < 4; ++r) {
          const float u = aU[i][j][r] + bu;
          const float v = aV[i][j][r] + bv;
          G[(long)(mb + r) * ldG + n] = f2b((u / (1.0f + __expf(-u))) * v);
        }
      }
    } else if (n < Npad) {
#pragma unroll
      for (int i = 0; i < 4; ++i) {
        const int mb = m0 + wm * 64 + i * 16 + lg * 4;
#pragma unroll
        for (int r = 0; r < 4; ++r) G[(long)(mb + r) * ldG + n] = 0;
      }
    }
  }
}

// ---------- LN over 512 (no affine; affine folded into Wqkv), f32 in, bf16 out ----------
__global__ __launch_bounds__(256) void pz_ln(const float* __restrict__ X, u16* __restrict__ O)
{
  __shared__ float sm[4], sq[4];
  const int tid = threadIdx.x;
  const long row = blockIdx.x;
  const float* x = X + row * 512;
  float a = x[tid], b = x[tid + 256];
  float s = a + b, q = a * a + b * b;
#pragma unroll
  for (int m = 32; m >= 1; m >>= 1) { s += __shfl_xor(s, m, 64); q += __shfl_xor(q, m, 64); }
  if ((tid & 63) == 0) { sm[tid >> 6] = s; sq[tid >> 6] = q; }
  __syncthreads();
  s = sm[0] + sm[1] + sm[2] + sm[3];
  q = sq[0] + sq[1] + sq[2] + sq[3];
  const float mean = s * (1.0f / 512.0f);
  const float rstd = rsqrtf(q * (1.0f / 512.0f) - mean * mean + 1e-5f);
  O[row * 512 + tid]       = f2b((a - mean) * rstd);
  O[row * 512 + tid + 256] = f2b((b - mean) * rstd);
}

// ---------- LN over concat(sctx_row[512] bf16, tmean_b[512] f32) -> h bf16 (1024) ----------
__global__ __launch_bounds__(256) void pz_mix_ln(
    const u16* __restrict__ SC, const float* __restrict__ TM,
    const float* __restrict__ g, const float* __restrict__ b, u16* __restrict__ H)
{
  __shared__ float sm[4], sq[4];
  const int tid = threadIdx.x;
  const long row = blockIdx.x;
  const int bb = (int)(row >> 12);
  const u16* x0 = SC + row * 512;
  const float* x1 = TM + (long)bb * 512;
  float v0 = b2f(x0[tid]), v1 = b2f(x0[tid + 256]);
  float v2 = x1[tid], v3 = x1[tid + 256];
  float s = v0 + v1 + v2 + v3;
  float q = v0 * v0 + v1 * v1 + v2 * v2 + v3 * v3;
#pragma unroll
  for (int m = 32; m >= 1; m >>= 1) { s += __shfl_xor(s, m, 64); q += __shfl_xor(q, m, 64); }
  if ((tid & 63) == 0) { sm[tid >> 6] = s; sq[tid >> 6] = q; }
  __syncthreads();
  s = sm[0] + sm[1] + sm[2] + sm[3];
  q = sq[0] + sq[1] + sq[2] + sq[3];
  const float mean = s * (1.0f / 1024.0f);
  const float rstd = rsqrtf(q * (1.0f / 1024.0f) - mean * mean + 1e-5f);
  u16* hr = H + row * 1024;
  hr[tid]       = f2b((v0 - mean) * rstd * g[tid]       + b[tid]);
  hr[tid + 256] = f2b((v1 - mean) * rstd * g[tid + 256] + b[tid + 256]);
  hr[tid + 512] = f2b((v2 - mean) * rstd * g[tid + 512] + b[tid + 512]);
  hr[tid + 768] = f2b((v3 - mean) * rstd * g[tid + 768] + b[tid + 768]);
}

// ---------- in-place row softmax on bf16 scores ----------
template <int L>
__global__ __launch_bounds__(256) void pz_softmax(u16* __restrict__ S)
{
  __shared__ float sm[4], ss[4];
  const int tid = threadIdx.x;
  const long row = blockIdx.x;
  u16* p = S + row * (long)L;
  constexpr int per = L >> 8;
  float v[per];
  float mx = -3.0e38f;
#pragma unroll
  for (int i = 0; i < per; ++i) { v[i] = b2f(p[tid + (i << 8)]); mx = fmaxf(mx, v[i]); }
#pragma unroll
  for (int m = 32; m >= 1; m >>= 1) mx = fmaxf(mx, __shfl_xor(mx, m, 64));
  if ((tid & 63) == 0) sm[tid >> 6] = mx;
  __syncthreads();
  mx = fmaxf(fmaxf(sm[0], sm[1]), fmaxf(sm[2], sm[3]));
  float s = 0.0f;
#pragma unroll
  for (int i = 0; i < per; ++i) { v[i] = __expf(v[i] - mx); s += v[i]; }
#pragma unroll
  for (int m = 32; m >= 1; m >>= 1) s += __shfl_xor(s, m, 64);
  if ((tid & 63) == 0) ss[tid >> 6] = s;
  __syncthreads();
  const float inv = 1.0f / (ss[0] + ss[1] + ss[2] + ss[3]);
#pragma unroll
  for (int i = 0; i < per; ++i) p[tid + (i << 8)] = f2b(v[i] * inv);
}

// ---------- bf16 slice transpose: D[(z*64+d)*Nk + nk] = S[nk*ldS + colBase + z*64 + d] ----------
__global__ __launch_bounds__(256) void pz_transpose(
    const u16* __restrict__ S, u16* __restrict__ D, int Nk, int ldS, int colBase)
{
  __shared__ u16 t[64][65];
  const int z = blockIdx.z;
  const int nk0 = blockIdx.x * 64;
  const int tid = threadIdx.x;
  for (int i = tid; i < 4096; i += 256) {
    int r = i >> 6, d = i & 63;
    t[r][d] = S[(long)(nk0 + r) * ldS + colBase + z * 64 + d];
  }
  __syncthreads();
  for (int i = tid; i < 4096; i += 256) {
    int d = i >> 6, c = i & 63;
    D[((long)z * 64 + d) * Nk + nk0 + c] = t[c][d];
  }
}

// ---------- f32 transpose + convert to bf16 (for Wo^T) ----------
__global__ __launch_bounds__(256) void pz_transpose_f2b(
    const float* __restrict__ S, u16* __restrict__ D, int Nk, int ldS)
{
  __shared__ u16 t[64][65];
  const int z = blockIdx.z;
  const int nk0 = blockIdx.x * 64;
  const int tid = threadIdx.x;
  for (int i = tid; i < 4096; i += 256) {
    int r = i >> 6, d = i & 63;
    t[r][d] = f2b(S[(long)(nk0 + r) * ldS + z * 64 + d]);
  }
  __syncthreads();
  for (int i = tid; i < 4096; i += 256) {
    int d = i >> 6, c = i & 63;
    D[((long)z * 64 + d) * Nk + nk0 + c] = t[c][d];
  }
}

// ---------- f32 -> bf16 flat convert ----------
__global__ __launch_bounds__(256) void pz_f2b(const float* __restrict__ s, u16* __restrict__ d, int n)
{
  int i = blockIdx.x * 256 + threadIdx.x;
  if (i < n) d[i] = f2b(s[i]);
}

// ---------- fold LN affine into Wqkv: W' = bf16(W*g(col)), b' = bqkv + W.b_ln (f32 in) ----------
__global__ __launch_bounds__(256) void pz_fold_qkv(
    const float* __restrict__ Ws, const float* __restrict__ Wt,
    const float* __restrict__ bs, const float* __restrict__ bt,
    const float* s_qg, const float* s_qb, const float* s_kg, const float* s_kb,
    const float* t_qg, const float* t_qb, const float* t_kg, const float* t_kb,
    u16* __restrict__ Wps, u16* __restrict__ Wpt, float* bps, float* bpt)
{
  __shared__ float sb[4];
  const int id = blockIdx.x;
  const int mat = (id >= 1536) ? 1 : 0;
  const int r = id - mat * 1536;
  const float* W = mat ? Wt : Ws;
  const float* bq = mat ? bt : bs;
  const float *g, *bl;
  if (!mat) { g = (r < 512) ? s_qg : s_kg; bl = (r < 512) ? s_qb : s_kb; }
  else      { g = (r < 512) ? t_qg : t_kg; bl = (r < 512) ? t_qb : t_kb; }
  u16* Wo_ = mat ? Wpt : Wps;
  float* bo_ = mat ? bpt : bps;
  float dot = 0.0f;
  for (int c = threadIdx.x; c < 512; c += 256) {
    float w = W[(long)r * 512 + c];
    Wo_[(long)r * 512 + c] = f2b(w * g[c]);
    dot += w * bl[c];
  }
#pragma unroll
  for (int m = 32; m >= 1; m >>= 1) dot += __shfl_xor(dot, m, 64);
  if ((threadIdx.x & 63) == 0) sb[threadIdx.x >> 6] = dot;
  __syncthreads();
  if (threadIdx.x == 0) bo_[r] = sb[0] + sb[1] + sb[2] + sb[3] + bq[r];
}

// ---------- combined proj bias: bc = Wp . bo + bp (f32) ----------
__global__ __launch_bounds__(256) void pz_fold_bc(
    const float* Wps_, const float* bos, const float* bps_,
    const float* Wpt_, const float* bot, const float* bpt_, float* bcs, float* bct)
{
  __shared__ float sb[4];
  const int id = blockIdx.x;
  const int mat = id >> 9, i = id & 511;
  const float* W = mat ? Wpt_ : Wps_;
  const float* bo = mat ? bot : bos;
  const float* bp = mat ? bpt_ : bps_;
  float* o = mat ? bct : bcs;
  float dot = 0.0f;
  for (int j = threadIdx.x; j < 512; j += 256) dot += W[(long)i * 512 + j] * bo[j];
#pragma unroll
  for (int m = 32; m >= 1; m >>= 1) dot += __shfl_xor(dot, m, 64);
  if ((threadIdx.x & 63) == 0) sb[threadIdx.x >> 6] = dot;
  __syncthreads();
  if (threadIdx.x == 0) o[i] = sb[0] + sb[1] + sb[2] + sb[3] + bp[i];
}

// ---------- Wout zero-pad 2730 -> 2752 cols (f32 -> bf16) ----------
__global__ __launch_bounds__(256) void pz_pad_wout(const float* __restrict__ W, u16* __restrict__ D)
{
  const int idx = blockIdx.x * 256 + threadIdx.x;  // grid covers 512*2752 exactly
  const int r = idx / 2752, c = idx - r * 2752;
  D[idx] = (c < 2730) ? f2b(W[(long)r * 2730 + c]) : (u16)0;
}

// ---------- t_ctx mean over tokens (tctx bf16; O f32 must be zeroed) ----------
__global__ __launch_bounds__(256) void pz_tmean(const u16* __restrict__ T, float* __restrict__ O)
{
  const int b = blockIdx.y, tc = blockIdx.x, tid = threadIdx.x;
  const u16* base = T + (long)b * 512 * 512 + (long)tc * 32 * 512;
  float s0 = 0.0f, s1 = 0.0f;
#pragma unroll 4
  for (int t = 0; t < 32; ++t) { s0 += b2f(base[t * 512 + tid]); s1 += b2f(base[t * 512 + tid + 256]); }
  atomicAdd(&O[b * 512 + tid],       s0 * (1.0f / 512.0f));
  atomicAdd(&O[b * 512 + tid + 256], s1 * (1.0f / 512.0f));
}

// ---------- diagnostic fill (reports ws_size in MB via absmax if ws too small) ----------
__global__ void pz_diag(float* __restrict__ out, long n, float val)
{
  for (long i = (long)blockIdx.x * 256 + threadIdx.x; i < n; i += (long)gridDim.x * 256)
    out[i] = val;
}

// ---------- host ----------
extern "C" void kernel_launch(void* const* d_in, const int* in_sizes, int n_in,
                              void* d_out, int out_size, void* d_ws, size_t ws_size,
                              hipStream_t stream)
{
  (void)in_sizes; (void)n_in;
  const float* spat   = (const float*)d_in[0];
  const float* temp   = (const float*)d_in[1];
  const float* s_qg = (const float*)d_in[2],  * s_qb = (const float*)d_in[3];
  const float* s_kg = (const float*)d_in[4],  * s_kb = (const float*)d_in[5];
  const float* s_Wqkv = (const float*)d_in[6], * s_bqkv = (const float*)d_in[7];
  const float* s_Wo = (const float*)d_in[8],  * s_bo = (const float*)d_in[9];
  const float* s_Wp = (const float*)d_in[10], * s_bp = (const float*)d_in[11];
  const float* t_qg = (const float*)d_in[12], * t_qb = (const float*)d_in[13];
  const float* t_kg = (const float*)d_in[14], * t_kb = (const float*)d_in[15];
  const float* t_Wqkv = (const float*)d_in[16], * t_bqkv = (const float*)d_in[17];
  const float* t_Wo = (const float*)d_in[18], * t_bo = (const float*)d_in[19];
  const float* t_Wp = (const float*)d_in[20], * t_bp = (const float*)d_in[21];
  const float* mix_g = (const float*)d_in[22], * mix_b = (const float*)d_in[23];
  const float* mix_Win = (const float*)d_in[24], * mix_bin = (const float*)d_in[25];
  const float* mix_Wout = (const float*)d_in[26], * mix_bout = (const float*)d_in[27];
  float* out = (float*)d_out;

  char* ws = (char*)d_ws;
  size_t off = 0;
  auto take = [&](size_t n) { void* p = ws + off; off += (n + 255) & ~(size_t)255; return p; };

  u16* wq_s  = (u16*)take(1536L * 512 * 2);   // folded s_Wqkv' (bf16)
  u16* wq_t  = (u16*)take(1536L * 512 * 2);
  u16* wc_s  = (u16*)take(512L * 512 * 2);    // Wp.Wo combined (bf16)
  u16* wc_t  = (u16*)take(512L * 512 * 2);
  u16* woutp = (u16*)take(512L * 2752 * 2);   // Wout zero-padded (bf16)
  float* bqs = (float*)take(1536L * 4);
  float* bqt = (float*)take(1536L * 4);
  float* bcs = (float*)take(512L * 4);
  float* bct = (float*)take(512L * 4);
  // A region: nhat -> later ctx
  u16* nhat_s = (u16*)take(16384L * 512 * 2);   // -> ctx_s
  u16* nhat_t = (u16*)take(2048L * 512 * 2);    // -> ctx_t
  // B region: qkv -> later sctx/tctx/tmean/hbuf
  u16* q_s  = (u16*)take(16384L * 512 * 2);     // -> sctx (bf16)
  u16* kv_s = (u16*)take(2048L * 1024 * 2);     // -> tctx (bf16)
  u16* q_t  = (u16*)take(2048L * 512 * 2);      // -> tmean (f32, 8KB)
  u16* kv_t = (u16*)take(16384L * 1024 * 2);    // -> hbuf (bf16)
  // S region: precompute scratch -> Sb|vt_s|vtc(+pv scratch) -> gchunk|winb
  char* Sreg = (char*)take(16777216 + 2097152 + 4194304);
  const size_t NEED = off;

  if (ws_size < NEED) {  // diagnostic: absmax will report ws budget in MB
    pz_diag<<<2048, 256, 0, stream>>>(out, (long)out_size, (float)(ws_size >> 20));
    return;
  }

  u16* wtT  = (u16*)Sreg;                    // 0.5MB precompute scratch
  u16* wpb  = (u16*)(Sreg + 524288);         // 0.5MB precompute scratch
  u16* Sb   = (u16*)Sreg;
  u16* vt_s = (u16*)(Sreg + 16777216);
  u16* vtc  = (u16*)(Sreg + 16777216 + 2097152);
  float* pvs_sp = (float*)vtc;               // spatial PV scratch (4MB; vtc idle then)
  float* pvs_t  = (float*)(Sreg + 8388608);  // temporal PV scratch (256KB; Sb uses 8MB)
  u16* ctx_s = nhat_s;
  u16* ctx_t = nhat_t;
  u16* sctx  = q_s;
  u16* tctx  = kv_s;
  float* tmean = (float*)q_t;
  u16* hbuf  = kv_t;
  u16* gchunk = (u16*)Sreg;
  u16* winb   = (u16*)(Sreg + 11272192);

  auto gemm = [&](const u16* A, const u16* B, const float* bias,
                  const u16* residB, const float* residF, u16* Cb, float* Cf,
                  int M, int N, int K, int ldA, int ldB, int ldC, int ldR,
                  long aSH, long bSH, long cSH, long rSH, int Z, float alpha) {
    dim3 g((N + 127) / 128, M / 128, Z);
    pz_gemm_bt<<<g, dim3(256), 0, stream>>>(A, B, bias, residB, residF, Cb, Cf,
        M, N, K, ldA, ldB, ldC, ldR, aSH, bSH, cSH, rSH, alpha);
  };

  // --- precompute: fold LN->Wqkv, Wc = Wp.Wo (bf16 GEMM), Wout pad, biases ---
  pz_fold_qkv<<<3072, 256, 0, stream>>>(s_Wqkv, t_Wqkv, s_bqkv, t_bqkv,
      s_qg, s_qb, s_kg, s_kb, t_qg, t_qb, t_kg, t_kb, wq_s, wq_t, bqs, bqt);
  pz_transpose_f2b<<<dim3(8, 1, 8), 256, 0, stream>>>(s_Wo, wtT, 512, 512);
  pz_f2b<<<1024, 256, 0, stream>>>(s_Wp, wpb, 512 * 512);
  gemm(wpb, wtT, nullptr, nullptr, nullptr, wc_s, nullptr,
       512, 512, 512, 512, 512, 512, 0, 0, 0, 0, 0, 1, 1.0f);
  pz_transpose_f2b<<<dim3(8, 1, 8), 256, 0, stream>>>(t_Wo, wtT, 512, 512);
  pz_f2b<<<1024, 256, 0, stream>>>(t_Wp, wpb, 512 * 512);
  gemm(wpb, wtT, nullptr, nullptr, nullptr, wc_t, nullptr,
       512, 512, 512, 512, 512, 512, 0, 0, 0, 0, 0, 1, 1.0f);
  pz_fold_bc<<<1024, 256, 0, stream>>>(s_Wp, s_bo, s_bp, t_Wp, t_bo, t_bp, bcs, bct);
  pz_pad_wout<<<5504, 256, 0, stream>>>(mix_Wout, woutp);

  // --- LN (normalized only; affine folded) ---
  pz_ln<<<16384, 256, 0, stream>>>(spat, nhat_s);
  pz_ln<<<2048, 256, 0, stream>>>(temp, nhat_t);

  // --- QKV projections ---
  gemm(nhat_s, wq_s,           bqs,       nullptr, nullptr, q_s,  nullptr,
       16384, 512,  512, 512, 512, 512,  0, 0,0,0,0, 1, 1.0f);
  gemm(nhat_t, wq_s + 512*512, bqs + 512, nullptr, nullptr, kv_s, nullptr,
       2048,  1024, 512, 512, 512, 1024, 0, 0,0,0,0, 1, 1.0f);
  gemm(nhat_t, wq_t,           bqt,       nullptr, nullptr, q_t,  nullptr,
       2048,  512,  512, 512, 512, 512,  0, 0,0,0,0, 1, 1.0f);
  gemm(nhat_s, wq_t + 512*512, bqt + 512, nullptr, nullptr, kv_t, nullptr,
       16384, 1024, 512, 512, 512, 1024, 0, 0,0,0,0, 1, 1.0f);

  // --- spatial-query attention (chunk: batch x 4 heads; S chunk = 16MB) ---
  for (int b = 0; b < 4; ++b)
    pz_transpose<<<dim3(8, 1, 8), 256, 0, stream>>>(kv_s + (long)b * 512 * 1024,
        vt_s + (long)b * 8 * 64 * 512, 512, 1024, 512);
  for (int b = 0; b < 4; ++b)
    for (int hc = 0; hc < 2; ++hc) {
      const u16* Aq = q_s + (long)b * 4096 * 512 + hc * 256;
      const u16* Bk = kv_s + (long)b * 512 * 1024 + hc * 256;
      gemm(Aq, Bk, nullptr, nullptr, nullptr, Sb, nullptr,
           4096, 512, 64, 512, 1024, 512, 0, 64, 64, 4096L * 512, 0, 4, 0.125f);
      pz_softmax<512><<<16384, 256, 0, stream>>>(Sb);
      const u16* Bv = vt_s + ((long)b * 8 + hc * 4) * 64 * 512;
      (void)hipMemsetAsync(pvs_sp, 0, 4L * 4096 * 64 * 4, stream);
      pz_gemm_pv<<<dim3(2, 32, 4), 256, 0, stream>>>(Sb, Bv, pvs_sp,
           4096, 512, 512, 4096L * 512, 64L * 512, 4096L * 64, 256);
      pz_pv_fin<<<4096, 256, 0, stream>>>(pvs_sp,
           ctx_s + (long)b * 4096 * 512 + hc * 256, 4096, 512);
    }

  // --- temporal-query attention (chunk: batch x head-pair; S chunk = 8MB) ---
  for (int b = 0; b < 4; ++b) {
    const u16* Bk = kv_t + (long)b * 4096 * 1024;
    pz_transpose<<<dim3(64, 1, 8), 256, 0, stream>>>(Bk, vtc, 4096, 1024, 512);
    for (int hp = 0; hp < 4; ++hp) {
      const u16* Aq = q_t + (long)b * 512 * 512 + hp * 128;
      gemm(Aq, Bk + hp * 128, nullptr, nullptr, nullptr, Sb, nullptr,
           512, 4096, 64, 512, 1024, 4096, 0, 64, 64, 512L * 4096, 0, 2, 0.125f);
      pz_softmax<4096><<<1024, 256, 0, stream>>>(Sb);
      (void)hipMemsetAsync(pvs_t, 0, 2L * 512 * 64 * 4, stream);
      pz_gemm_pv<<<dim3(16, 4, 2), 256, 0, stream>>>(Sb, vtc + (long)hp * 2 * 64 * 4096,
           pvs_t, 512, 4096, 4096, 512L * 4096, 64L * 4096, 512L * 64, 256);
      pz_pv_fin<<<256, 256, 0, stream>>>(pvs_t,
           ctx_t + (long)b * 512 * 512 + hp * 128, 512, 512);
    }
  }

  // --- combined output projection (Wc = Wp.Wo) + f32 residual -> bf16 ctx ---
  gemm(ctx_s, wc_s, bcs, nullptr, spat, sctx, nullptr,
       16384, 512, 512, 512, 512, 512, 512, 0,0,0,0, 1, 1.0f);
  gemm(ctx_t, wc_t, bct, nullptr, temp, tctx, nullptr,
       2048,  512, 512, 512, 512, 512, 512, 0,0,0,0, 1, 1.0f);

  // --- t_mean + mix LN ---
  (void)hipMemsetAsync(tmean, 0, 4L * 512 * sizeof(float), stream);
  pz_tmean<<<dim3(16, 4), 256, 0, stream>>>(tctx, tmean);
  pz_mix_ln<<<16384, 256, 0, stream>>>(sctx, tmean, mix_g, mix_b, hbuf);

  // --- mix_Win -> bf16 (Sreg free now; winb behind gchunk) ---
  pz_f2b<<<21840, 256, 0, stream>>>(mix_Win, winb, 5460 * 1024);

  // --- mix MLP in 8 row-chunks of 2048: fused u/v+gate GEMM, then Wout GEMM + resid ---
  for (int c = 0; c < 8; ++c) {
    const u16* Ah = hbuf + (long)c * 2048 * 1024;
    pz_gemm_uvgate<<<dim3(22, 16), 256, 0, stream>>>(Ah, winb, winb + 2730L * 1024,
        mix_bin, mix_bin + 2730, gchunk, 2048, 2730, 1024, 1024, 1024, 2752, 2752);
    gemm(gchunk, woutp, mix_bout, sctx + (long)c * 2048 * 512, nullptr,
         nullptr, out + (long)c * 2048 * 512,
         2048, 512, 2752, 2752, 2752, 512, 512, 0,0,0,0, 1, 1.0f);
  }
}

// Round 7
// 1920.567 us; speedup vs baseline: 2.0250x; 1.3858x over previous
//
#include <hip/hip_runtime.h>
#include <stdint.h>

typedef unsigned short u16;
typedef __bf16 bf16_t;
typedef bf16_t bf16x8 __attribute__((ext_vector_type(8)));
typedef float f32x4 __attribute__((ext_vector_type(4)));

// ---------- helpers ----------
__device__ __forceinline__ u16 f2b(float f) {
  union { float f; uint32_t u; } x; x.f = f;
  uint32_t r = x.u + 0x7fffu + ((x.u >> 16) & 1u);
  return (u16)(r >> 16);
}
__device__ __forceinline__ float b2f(u16 b) {
  union { uint32_t u; float f; } x; x.u = ((uint32_t)b) << 16;
  return x.f;
}

// async global->LDS, 16B per lane. LDS dest = wave-uniform base + lane*16.
__device__ __forceinline__ void async16(const void* g, void* l) {
  auto gp = reinterpret_cast<__attribute__((address_space(1))) unsigned int*>(
      reinterpret_cast<uintptr_t>(g));
  auto lp = reinterpret_cast<__attribute__((address_space(3))) unsigned int*>(
      reinterpret_cast<uintptr_t>(l));
  __builtin_amdgcn_global_load_lds(gp, lp, 16, 0, 0);
}

// ---------- generic bf16 MFMA GEMM:  C = alpha*A(MxK)*B(NxK)^T + bias [+resid] ----------
__global__ __launch_bounds__(256) void pz_gemm_bt(
    const u16* __restrict__ A, const u16* __restrict__ B,
    const float* __restrict__ bias,
    const u16* __restrict__ residB, const float* __restrict__ residF,
    u16* __restrict__ Cb, float* __restrict__ Cf,
    int M, int N, int K, int ldA, int ldB, int ldC, int ldR,
    long aSH, long bSH, long cSH, long rSH, float alpha)
{
  __shared__ __align__(16) u16 sA[128 * 32];
  __shared__ __align__(16) u16 sB[128 * 32];

  const int tid = threadIdx.x;
  const int wave = tid >> 6, lane = tid & 63;
  const int lr = lane & 15, lg = lane >> 4;
  const int wm = wave >> 1, wn = wave & 1;
  const int z = blockIdx.z;

  const u16* Ab = A + (long)z * aSH;
  const u16* Bb = B + (long)z * bSH;
  const int m0 = blockIdx.y * 128;
  const int n0 = blockIdx.x * 128;

  const int srow = tid >> 2;
  const int sgk = (tid & 3) ^ ((tid >> 3) & 3);
  int ar0 = m0 + srow;      if (ar0 > M - 1) ar0 = M - 1;
  int ar1 = m0 + 64 + srow; if (ar1 > M - 1) ar1 = M - 1;
  int br0 = n0 + srow;      if (br0 > N - 1) br0 = N - 1;
  int br1 = n0 + 64 + srow; if (br1 > N - 1) br1 = N - 1;
  const u16* aP0 = Ab + (long)ar0 * ldA + sgk * 8;
  const u16* aP1 = Ab + (long)ar1 * ldA + sgk * 8;
  const u16* bP0 = Bb + (long)br0 * ldB + sgk * 8;
  const u16* bP1 = Bb + (long)br1 * ldB + sgk * 8;
  u16* sAw0 = sA + wave * 512;
  u16* sAw1 = sA + 2048 + wave * 512;
  u16* sBw0 = sB + wave * 512;
  u16* sBw1 = sB + 2048 + wave * 512;

  const int swz = (lr >> 1) & 3;
  int aoff[4], boff[4];
#pragma unroll
  for (int i = 0; i < 4; ++i) {
    aoff[i] = (wm * 64 + i * 16 + lr) * 32 + ((lg ^ swz) * 8);
    boff[i] = (wn * 64 + i * 16 + lr) * 32 + ((lg ^ swz) * 8);
  }

  f32x4 acc[4][4] = {};
  const int kiters = K >> 5;
  for (int kt = 0; kt < kiters; ++kt) {
    const int k0 = kt << 5;
    __syncthreads();
    async16(aP0 + k0, sAw0);
    async16(aP1 + k0, sAw1);
    async16(bP0 + k0, sBw0);
    async16(bP1 + k0, sBw1);
    __builtin_amdgcn_s_waitcnt(0x0f70);  // vmcnt(0)
    __syncthreads();

    bf16x8 af[4], bfr[4];
#pragma unroll
    for (int i = 0; i < 4; ++i) af[i] = *(const bf16x8*)(sA + aoff[i]);
#pragma unroll
    for (int i = 0; i < 4; ++i) bfr[i] = *(const bf16x8*)(sB + boff[i]);
#pragma unroll
    for (int i = 0; i < 4; ++i)
#pragma unroll
      for (int j = 0; j < 4; ++j)
        acc[i][j] = __builtin_amdgcn_mfma_f32_16x16x32_bf16(af[i], bfr[j], acc[i][j], 0, 0, 0);
  }

  // C/D layout: col = lane&15, row = (lane>>4)*4 + reg  [m89/m91]
  const long coff = (long)z * cSH;
  const long roff = (long)z * rSH;
#pragma unroll
  for (int j = 0; j < 4; ++j) {
    const int n = n0 + wn * 64 + j * 16 + lr;
    if (n < N) {
      const float bv = bias ? bias[n] : 0.0f;
#pragma unroll
      for (int i = 0; i < 4; ++i) {
        const int mb = m0 + wm * 64 + i * 16 + lg * 4;
#pragma unroll
        for (int r = 0; r < 4; ++r) {
          const int m = mb + r;
          float v = alpha * acc[i][j][r] + bv;
          const long ri = roff + (long)m * ldR + n;
          if (residB) v += b2f(residB[ri]);
          if (residF) v += residF[ri];
          const long ci = coff + (long)m * ldC + n;
          if (Cb) Cb[ci] = f2b(v);
          if (Cf) Cf[ci] = v;
        }
      }
    }
  }
}

// ---------- split-K GEMM: C(MxN) += A(MxK_chunk)*B(NxK_chunk)^T, f32 atomic out ----------
// blockIdx.z = K-split. C must be pre-initialized (bias+resid). 128x128 tile.
__global__ __launch_bounds__(256) void pz_gemm_sk(
    const u16* __restrict__ A, const u16* __restrict__ B, float* __restrict__ C,
    int M, int N, int ldA, int ldB, int ldC, int kchunk)
{
  __shared__ __align__(16) u16 sA[128 * 32];
  __shared__ __align__(16) u16 sB[128 * 32];

  const int tid = threadIdx.x;
  const int wave = tid >> 6, lane = tid & 63;
  const int lr = lane & 15, lg = lane >> 4;
  const int wm = wave >> 1, wn = wave & 1;
  const int m0 = blockIdx.y * 128;
  const int n0 = blockIdx.x * 128;
  const int kbase = blockIdx.z * kchunk;

  const int srow = tid >> 2;
  const int sgk = (tid & 3) ^ ((tid >> 3) & 3);
  const u16* aP0 = A + (long)(m0 + srow) * ldA + sgk * 8;
  const u16* aP1 = A + (long)(m0 + 64 + srow) * ldA + sgk * 8;
  const u16* bP0 = B + (long)(n0 + srow) * ldB + sgk * 8;
  const u16* bP1 = B + (long)(n0 + 64 + srow) * ldB + sgk * 8;
  u16* sAw0 = sA + wave * 512;
  u16* sAw1 = sA + 2048 + wave * 512;
  u16* sBw0 = sB + wave * 512;
  u16* sBw1 = sB + 2048 + wave * 512;

  const int swz = (lr >> 1) & 3;
  int aoff[4], boff[4];
#pragma unroll
  for (int i = 0; i < 4; ++i) {
    aoff[i] = (wm * 64 + i * 16 + lr) * 32 + ((lg ^ swz) * 8);
    boff[i] = (wn * 64 + i * 16 + lr) * 32 + ((lg ^ swz) * 8);
  }

  f32x4 acc[4][4] = {};
  const int kiters = kchunk >> 5;
  for (int kt = 0; kt < kiters; ++kt) {
    const int k0 = kbase + (kt << 5);
    __syncthreads();
    async16(aP0 + k0, sAw0);
    async16(aP1 + k0, sAw1);
    async16(bP0 + k0, sBw0);
    async16(bP1 + k0, sBw1);
    __builtin_amdgcn_s_waitcnt(0x0f70);
    __syncthreads();

    bf16x8 af[4], bfr[4];
#pragma unroll
    for (int i = 0; i < 4; ++i) af[i] = *(const bf16x8*)(sA + aoff[i]);
#pragma unroll
    for (int i = 0; i < 4; ++i) bfr[i] = *(const bf16x8*)(sB + boff[i]);
#pragma unroll
    for (int i = 0; i < 4; ++i)
#pragma unroll
      for (int j = 0; j < 4; ++j)
        acc[i][j] = __builtin_amdgcn_mfma_f32_16x16x32_bf16(af[i], bfr[j], acc[i][j], 0, 0, 0);
  }

#pragma unroll
  for (int j = 0; j < 4; ++j) {
    const int n = n0 + wn * 64 + j * 16 + lr;
#pragma unroll
    for (int i = 0; i < 4; ++i) {
      const int mb = m0 + wm * 64 + i * 16 + lg * 4;
#pragma unroll
      for (int r = 0; r < 4; ++r)
        atomicAdd(&C[(long)(mb + r) * ldC + n], acc[i][j][r]);
    }
  }
}

// ---------- split-K P.V GEMM: C(Mx64) += A(MxK).B(64xK)^T, f32 atomic out ----------
__global__ __launch_bounds__(256) void pz_gemm_pv(
    const u16* __restrict__ A, const u16* __restrict__ B, float* __restrict__ C,
    int M, int ldA, int ldB, long aSH, long bSH, long cSH, int kchunk)
{
  __shared__ __align__(16) u16 sA[128 * 32];
  __shared__ __align__(16) u16 sB[64 * 32];

  const int tid = threadIdx.x;
  const int wave = tid >> 6, lane = tid & 63;
  const int lr = lane & 15, lg = lane >> 4;
  const int wm = wave >> 1, wn = wave & 1;
  const int z = blockIdx.z;
  const int m0 = blockIdx.y * 128;
  const int kbase = blockIdx.x * kchunk;

  const u16* Ab = A + (long)z * aSH;
  const u16* Bb = B + (long)z * bSH;

  const int srow = tid >> 2;
  const int sgk = (tid & 3) ^ ((tid >> 3) & 3);
  const u16* aP0 = Ab + (long)(m0 + srow) * ldA + sgk * 8;
  const u16* aP1 = Ab + (long)(m0 + 64 + srow) * ldA + sgk * 8;
  const u16* bP  = Bb + (long)srow * ldB + sgk * 8;
  u16* sAw0 = sA + wave * 512;
  u16* sAw1 = sA + 2048 + wave * 512;
  u16* sBw  = sB + wave * 512;

  const int swz = (lr >> 1) & 3;
  int aoff[4], boff[2];
#pragma unroll
  for (int i = 0; i < 4; ++i) aoff[i] = (wm * 64 + i * 16 + lr) * 32 + ((lg ^ swz) * 8);
#pragma unroll
  for (int j = 0; j < 2; ++j) boff[j] = (wn * 32 + j * 16 + lr) * 32 + ((lg ^ swz) * 8);

  f32x4 acc[4][2] = {};
  const int kiters = kchunk >> 5;
  for (int kt = 0; kt < kiters; ++kt) {
    const int k0 = kbase + (kt << 5);
    __syncthreads();
    async16(aP0 + k0, sAw0);
    async16(aP1 + k0, sAw1);
    async16(bP  + k0, sBw);
    __builtin_amdgcn_s_waitcnt(0x0f70);
    __syncthreads();

    bf16x8 af[4], bfr[2];
#pragma unroll
    for (int i = 0; i < 4; ++i) af[i] = *(const bf16x8*)(sA + aoff[i]);
#pragma unroll
    for (int j = 0; j < 2; ++j) bfr[j] = *(const bf16x8*)(sB + boff[j]);
#pragma unroll
    for (int i = 0; i < 4; ++i)
#pragma unroll
      for (int j = 0; j < 2; ++j)
        acc[i][j] = __builtin_amdgcn_mfma_f32_16x16x32_bf16(af[i], bfr[j], acc[i][j], 0, 0, 0);
  }

  const long coff = (long)z * cSH;
#pragma unroll
  for (int j = 0; j < 2; ++j) {
    const int n = wn * 32 + j * 16 + lr;
#pragma unroll
    for (int i = 0; i < 4; ++i) {
      const int mb = m0 + wm * 64 + i * 16 + lg * 4;
#pragma unroll
      for (int r = 0; r < 4; ++r)
        atomicAdd(&C[coff + (long)(mb + r) * 64 + n], acc[i][j][r]);
    }
  }
}

// ---------- P.V finalize: f32 [z][M][64] -> bf16 dst[m*ldD + z*64 + d] ----------
__global__ __launch_bounds__(256) void pz_pv_fin(
    const float* __restrict__ S, u16* __restrict__ D, int M, int ldD)
{
  const long idx = (long)blockIdx.x * 256 + threadIdx.x;
  const int d = (int)(idx & 63);
  const long rem = idx >> 6;
  const int m = (int)(rem % M);
  const int z = (int)(rem / M);
  D[(long)m * ldD + z * 64 + d] = f2b(S[idx]);
}

// ---------- fused dual GEMM + SwiGLU gate: G = silu(A Bu^T + bu) * (A Bv^T + bv) ----------
__global__ __launch_bounds__(256) void pz_gemm_uvgate(
    const u16* __restrict__ A, const u16* __restrict__ Bu, const u16* __restrict__ Bv,
    const float* __restrict__ biasU, const float* __restrict__ biasV,
    u16* __restrict__ G, int M, int N, int K, int ldA, int ldB, int ldG, int Npad)
{
  __shared__ __align__(16) u16 sA[128 * 32];
  __shared__ __align__(16) u16 sU[128 * 32];
  __shared__ __align__(16) u16 sV[128 * 32];

  const int tid = threadIdx.x;
  const int wave = tid >> 6, lane = tid & 63;
  const int lr = lane & 15, lg = lane >> 4;
  const int wm = wave >> 1, wn = wave & 1;
  const int m0 = blockIdx.y * 128;
  const int n0 = blockIdx.x * 128;

  const int srow = tid >> 2;
  const int sgk = (tid & 3) ^ ((tid >> 3) & 3);
  int ar0 = m0 + srow;      if (ar0 > M - 1) ar0 = M - 1;
  int ar1 = m0 + 64 + srow; if (ar1 > M - 1) ar1 = M - 1;
  int br0 = n0 + srow;      if (br0 > N - 1) br0 = N - 1;
  int br1 = n0 + 64 + srow; if (br1 > N - 1) br1 = N - 1;
  const u16* aP0 = A + (long)ar0 * ldA + sgk * 8;
  const u16* aP1 = A + (long)ar1 * ldA + sgk * 8;
  const u16* uP0 = Bu + (long)br0 * ldB + sgk * 8;
  const u16* uP1 = Bu + (long)br1 * ldB + sgk * 8;
  const u16* vP0 = Bv + (long)br0 * ldB + sgk * 8;
  const u16* vP1 = Bv + (long)br1 * ldB + sgk * 8;
  u16* sAw0 = sA + wave * 512; u16* sAw1 = sA + 2048 + wave * 512;
  u16* sUw0 = sU + wave * 512; u16* sUw1 = sU + 2048 + wave * 512;
  u16* sVw0 = sV + wave * 512; u16* sVw1 = sV + 2048 + wave * 512;

  const int swz = (lr >> 1) & 3;
  int aoff[4], boff[4];
#pragma unroll
  for (int i = 0; i < 4; ++i) {
    aoff[i] = (wm * 64 + i * 16 + lr) * 32 + ((lg ^ swz) * 8);
    boff[i] = (wn * 64 + i * 16 + lr) * 32 + ((lg ^ swz) * 8);
  }

  f32x4 aU[4][4] = {}, aV[4][4] = {};
  const int kiters = K >> 5;
  for (int kt = 0; kt < kiters; ++kt) {
    const int k0 = kt << 5;
    __syncthreads();
    async16(aP0 + k0, sAw0);
    async16(aP1 + k0, sAw1);
    async16(uP0 + k0, sUw0);
    async16(uP1 + k0, sUw1);
    async16(vP0 + k0, sVw0);
    async16(vP1 + k0, sVw1);
    __builtin_amdgcn_s_waitcnt(0x0f70);
    __syncthreads();

    bf16x8 af[4], uf[4], vf[4];
#pragma unroll
    for (int i = 0; i < 4; ++i) af[i] = *(const bf16x8*)(sA + aoff[i]);
#pragma unroll
    for (int i = 0; i < 4; ++i) uf[i] = *(const bf16x8*)(sU + boff[i]);
#pragma unroll
    for (int i = 0; i < 4; ++i) vf[i] = *(const bf16x8*)(sV + boff[i]);
#pragma unroll
    for (int i = 0; i < 4; ++i)
#pragma unroll
      for (int j = 0; j < 4; ++j) {
        aU[i][j] = __builtin_amdgcn_mfma_f32_16x16x32_bf16(af[i], uf[j], aU[i][j], 0, 0, 0);
        aV[i][j] = __builtin_amdgcn_mfma_f32_16x16x32_bf16(af[i], vf[j], aV[i][j], 0, 0, 0);
      }
  }

#pragma unroll
  for (int j = 0; j < 4; ++j) {
    const int n = n0 + wn * 64 + j * 16 + lr;
    if (n < N) {
      const float bu = biasU[n], bv = biasV[n];
#pragma unroll
      for (int i = 0; i < 4; ++i) {
        const int mb = m0 + wm * 64 + i * 16 + lg * 4;
#pragma unroll
        for (int r = 0; r < 4; ++r) {
          const float u = aU[i][j][r] + bu;
          const float v = aV[i][j][r] + bv;
          G[(long)(mb + r) * ldG + n] = f2b((u / (1.0f + __expf(-u))) * v);
        }
      }
    } else if (n < Npad) {
#pragma unroll
      for (int i = 0; i < 4; ++i) {
        const int mb = m0 + wm * 64 + i * 16 + lg * 4;
#pragma unroll
        for (int r = 0; r < 4; ++r) G[(long)(mb + r) * ldG + n] = 0;
      }
    }
  }
}

// ---------- LN over 512 (no affine; affine folded into Wqkv), f32 in, bf16 out ----------
__global__ __launch_bounds__(256) void pz_ln(const float* __restrict__ X, u16* __restrict__ O)
{
  __shared__ float sm[4], sq[4];
  const int tid = threadIdx.x;
  const long row = blockIdx.x;
  const float* x = X + row * 512;
  float a = x[tid], b = x[tid + 256];
  float s = a + b, q = a * a + b * b;
#pragma unroll
  for (int m = 32; m >= 1; m >>= 1) { s += __shfl_xor(s, m, 64); q += __shfl_xor(q, m, 64); }
  if ((tid & 63) == 0) { sm[tid >> 6] = s; sq[tid >> 6] = q; }
  __syncthreads();
  s = sm[0] + sm[1] + sm[2] + sm[3];
  q = sq[0] + sq[1] + sq[2] + sq[3];
  const float mean = s * (1.0f / 512.0f);
  const float rstd = rsqrtf(q * (1.0f / 512.0f) - mean * mean + 1e-5f);
  O[row * 512 + tid]       = f2b((a - mean) * rstd);
  O[row * 512 + tid + 256] = f2b((b - mean) * rstd);
}

// ---------- LN over concat(sctx_row[512] bf16, tmean_b[512] f32) -> h bf16 (1024) ----------
__global__ __launch_bounds__(256) void pz_mix_ln(
    const u16* __restrict__ SC, const float* __restrict__ TM,
    const float* __restrict__ g, const float* __restrict__ b, u16* __restrict__ H)
{
  __shared__ float sm[4], sq[4];
  const int tid = threadIdx.x;
  const long row = blockIdx.x;
  const int bb = (int)(row >> 12);
  const u16* x0 = SC + row * 512;
  const float* x1 = TM + (long)bb * 512;
  float v0 = b2f(x0[tid]), v1 = b2f(x0[tid + 256]);
  float v2 = x1[tid], v3 = x1[tid + 256];
  float s = v0 + v1 + v2 + v3;
  float q = v0 * v0 + v1 * v1 + v2 * v2 + v3 * v3;
#pragma unroll
  for (int m = 32; m >= 1; m >>= 1) { s += __shfl_xor(s, m, 64); q += __shfl_xor(q, m, 64); }
  if ((tid & 63) == 0) { sm[tid >> 6] = s; sq[tid >> 6] = q; }
  __syncthreads();
  s = sm[0] + sm[1] + sm[2] + sm[3];
  q = sq[0] + sq[1] + sq[2] + sq[3];
  const float mean = s * (1.0f / 1024.0f);
  const float rstd = rsqrtf(q * (1.0f / 1024.0f) - mean * mean + 1e-5f);
  u16* hr = H + row * 1024;
  hr[tid]       = f2b((v0 - mean) * rstd * g[tid]       + b[tid]);
  hr[tid + 256] = f2b((v1 - mean) * rstd * g[tid + 256] + b[tid + 256]);
  hr[tid + 512] = f2b((v2 - mean) * rstd * g[tid + 512] + b[tid + 512]);
  hr[tid + 768] = f2b((v3 - mean) * rstd * g[tid + 768] + b[tid + 768]);
}

// ---------- in-place row softmax on bf16 scores ----------
template <int L>
__global__ __launch_bounds__(256) void pz_softmax(u16* __restrict__ S)
{
  __shared__ float sm[4], ss[4];
  const int tid = threadIdx.x;
  const long row = blockIdx.x;
  u16* p = S + row * (long)L;
  constexpr int per = L >> 8;
  float v[per];
  float mx = -3.0e38f;
#pragma unroll
  for (int i = 0; i < per; ++i) { v[i] = b2f(p[tid + (i << 8)]); mx = fmaxf(mx, v[i]); }
#pragma unroll
  for (int m = 32; m >= 1; m >>= 1) mx = fmaxf(mx, __shfl_xor(mx, m, 64));
  if ((tid & 63) == 0) sm[tid >> 6] = mx;
  __syncthreads();
  mx = fmaxf(fmaxf(sm[0], sm[1]), fmaxf(sm[2], sm[3]));
  float s = 0.0f;
#pragma unroll
  for (int i = 0; i < per; ++i) { v[i] = __expf(v[i] - mx); s += v[i]; }
#pragma unroll
  for (int m = 32; m >= 1; m >>= 1) s += __shfl_xor(s, m, 64);
  if ((tid & 63) == 0) ss[tid >> 6] = s;
  __syncthreads();
  const float inv = 1.0f / (ss[0] + ss[1] + ss[2] + ss[3]);
#pragma unroll
  for (int i = 0; i < per; ++i) p[tid + (i << 8)] = f2b(v[i] * inv);
}

// ---------- bf16 slice transpose ----------
__global__ __launch_bounds__(256) void pz_transpose(
    const u16* __restrict__ S, u16* __restrict__ D, int Nk, int ldS, int colBase)
{
  __shared__ u16 t[64][65];
  const int z = blockIdx.z;
  const int nk0 = blockIdx.x * 64;
  const int tid = threadIdx.x;
  for (int i = tid; i < 4096; i += 256) {
    int r = i >> 6, d = i & 63;
    t[r][d] = S[(long)(nk0 + r) * ldS + colBase + z * 64 + d];
  }
  __syncthreads();
  for (int i = tid; i < 4096; i += 256) {
    int d = i >> 6, c = i & 63;
    D[((long)z * 64 + d) * Nk + nk0 + c] = t[c][d];
  }
}

// ---------- f32 transpose + convert to bf16 (for Wo^T) ----------
__global__ __launch_bounds__(256) void pz_transpose_f2b(
    const float* __restrict__ S, u16* __restrict__ D, int Nk, int ldS)
{
  __shared__ u16 t[64][65];
  const int z = blockIdx.z;
  const int nk0 = blockIdx.x * 64;
  const int tid = threadIdx.x;
  for (int i = tid; i < 4096; i += 256) {
    int r = i >> 6, d = i & 63;
    t[r][d] = f2b(S[(long)(nk0 + r) * ldS + z * 64 + d]);
  }
  __syncthreads();
  for (int i = tid; i < 4096; i += 256) {
    int d = i >> 6, c = i & 63;
    D[((long)z * 64 + d) * Nk + nk0 + c] = t[c][d];
  }
}

// ---------- f32 -> bf16 flat convert ----------
__global__ __launch_bounds__(256) void pz_f2b(const float* __restrict__ s, u16* __restrict__ d, int n)
{
  int i = blockIdx.x * 256 + threadIdx.x;
  if (i < n) d[i] = f2b(s[i]);
}

// ---------- fold LN affine into Wqkv ----------
__global__ __launch_bounds__(256) void pz_fold_qkv(
    const float* __restrict__ Ws, const float* __restrict__ Wt,
    const float* __restrict__ bs, const float* __restrict__ bt,
    const float* s_qg, const float* s_qb, const float* s_kg, const float* s_kb,
    const float* t_qg, const float* t_qb, const float* t_kg, const float* t_kb,
    u16* __restrict__ Wps, u16* __restrict__ Wpt, float* bps, float* bpt)
{
  __shared__ float sb[4];
  const int id = blockIdx.x;
  const int mat = (id >= 1536) ? 1 : 0;
  const int r = id - mat * 1536;
  const float* W = mat ? Wt : Ws;
  const float* bq = mat ? bt : bs;
  const float *g, *bl;
  if (!mat) { g = (r < 512) ? s_qg : s_kg; bl = (r < 512) ? s_qb : s_kb; }
  else      { g = (r < 512) ? t_qg : t_kg; bl = (r < 512) ? t_qb : t_kb; }
  u16* Wo_ = mat ? Wpt : Wps;
  float* bo_ = mat ? bpt : bps;
  float dot = 0.0f;
  for (int c = threadIdx.x; c < 512; c += 256) {
    float w = W[(long)r * 512 + c];
    Wo_[(long)r * 512 + c] = f2b(w * g[c]);
    dot += w * bl[c];
  }
#pragma unroll
  for (int m = 32; m >= 1; m >>= 1) dot += __shfl_xor(dot, m, 64);
  if ((threadIdx.x & 63) == 0) sb[threadIdx.x >> 6] = dot;
  __syncthreads();
  if (threadIdx.x == 0) bo_[r] = sb[0] + sb[1] + sb[2] + sb[3] + bq[r];
}

// ---------- combined proj bias: bc = Wp . bo + bp (f32) ----------
__global__ __launch_bounds__(256) void pz_fold_bc(
    const float* Wps_, const float* bos, const float* bps_,
    const float* Wpt_, const float* bot, const float* bpt_, float* bcs, float* bct)
{
  __shared__ float sb[4];
  const int id = blockIdx.x;
  const int mat = id >> 9, i = id & 511;
  const float* W = mat ? Wpt_ : Wps_;
  const float* bo = mat ? bot : bos;
  const float* bp = mat ? bpt_ : bps_;
  float* o = mat ? bct : bcs;
  float dot = 0.0f;
  for (int j = threadIdx.x; j < 512; j += 256) dot += W[(long)i * 512 + j] * bo[j];
#pragma unroll
  for (int m = 32; m >= 1; m >>= 1) dot += __shfl_xor(dot, m, 64);
  if ((threadIdx.x & 63) == 0) sb[threadIdx.x >> 6] = dot;
  __syncthreads();
  if (threadIdx.x == 0) o[i] = sb[0] + sb[1] + sb[2] + sb[3] + bp[i];
}

// ---------- Wout zero-pad 2730 -> 2816 cols (f32 -> bf16) ----------
__global__ __launch_bounds__(256) void pz_pad_wout(const float* __restrict__ W, u16* __restrict__ D)
{
  const int idx = blockIdx.x * 256 + threadIdx.x;  // grid covers 512*2816 exactly
  const int r = idx / 2816, c = idx - r * 2816;
  D[idx] = (c < 2730) ? f2b(W[(long)r * 2730 + c]) : (u16)0;
}

// ---------- out init: out = mix_bout[n] + sctx (f32) ----------
__global__ __launch_bounds__(256) void pz_out_init(
    const float* __restrict__ bias, const u16* __restrict__ resid, float* __restrict__ O)
{
  const long i = (long)blockIdx.x * 256 + threadIdx.x;  // grid covers 16384*512
  O[i] = bias[i & 511] + b2f(resid[i]);
}

// ---------- t_ctx mean over tokens ----------
__global__ __launch_bounds__(256) void pz_tmean(const u16* __restrict__ T, float* __restrict__ O)
{
  const int b = blockIdx.y, tc = blockIdx.x, tid = threadIdx.x;
  const u16* base = T + (long)b * 512 * 512 + (long)tc * 32 * 512;
  float s0 = 0.0f, s1 = 0.0f;
#pragma unroll 4
  for (int t = 0; t < 32; ++t) { s0 += b2f(base[t * 512 + tid]); s1 += b2f(base[t * 512 + tid + 256]); }
  atomicAdd(&O[b * 512 + tid],       s0 * (1.0f / 512.0f));
  atomicAdd(&O[b * 512 + tid + 256], s1 * (1.0f / 512.0f));
}

// ---------- diagnostic fill ----------
__global__ void pz_diag(float* __restrict__ out, long n, float val)
{
  for (long i = (long)blockIdx.x * 256 + threadIdx.x; i < n; i += (long)gridDim.x * 256)
    out[i] = val;
}

// ---------- host ----------
extern "C" void kernel_launch(void* const* d_in, const int* in_sizes, int n_in,
                              void* d_out, int out_size, void* d_ws, size_t ws_size,
                              hipStream_t stream)
{
  (void)in_sizes; (void)n_in;
  const float* spat   = (const float*)d_in[0];
  const float* temp   = (const float*)d_in[1];
  const float* s_qg = (const float*)d_in[2],  * s_qb = (const float*)d_in[3];
  const float* s_kg = (const float*)d_in[4],  * s_kb = (const float*)d_in[5];
  const float* s_Wqkv = (const float*)d_in[6], * s_bqkv = (const float*)d_in[7];
  const float* s_Wo = (const float*)d_in[8],  * s_bo = (const float*)d_in[9];
  const float* s_Wp = (const float*)d_in[10], * s_bp = (const float*)d_in[11];
  const float* t_qg = (const float*)d_in[12], * t_qb = (const float*)d_in[13];
  const float* t_kg = (const float*)d_in[14], * t_kb = (const float*)d_in[15];
  const float* t_Wqkv = (const float*)d_in[16], * t_bqkv = (const float*)d_in[17];
  const float* t_Wo = (const float*)d_in[18], * t_bo = (const float*)d_in[19];
  const float* t_Wp = (const float*)d_in[20], * t_bp = (const float*)d_in[21];
  const float* mix_g = (const float*)d_in[22], * mix_b = (const float*)d_in[23];
  const float* mix_Win = (const float*)d_in[24], * mix_bin = (const float*)d_in[25];
  const float* mix_Wout = (const float*)d_in[26], * mix_bout = (const float*)d_in[27];
  float* out = (float*)d_out;

  char* ws = (char*)d_ws;
  size_t off = 0;
  auto take = [&](size_t n) { void* p = ws + off; off += (n + 255) & ~(size_t)255; return p; };

  u16* wq_s  = (u16*)take(1536L * 512 * 2);
  u16* wq_t  = (u16*)take(1536L * 512 * 2);
  u16* wc_s  = (u16*)take(512L * 512 * 2);
  u16* wc_t  = (u16*)take(512L * 512 * 2);
  u16* woutp = (u16*)take(512L * 2816 * 2);   // Wout zero-padded to K=2816
  float* bqs = (float*)take(1536L * 4);
  float* bqt = (float*)take(1536L * 4);
  float* bcs = (float*)take(512L * 4);
  float* bct = (float*)take(512L * 4);
  // A region: nhat -> ctx -> winb (mix phase)
  u16* nhat_s = (u16*)take(16384L * 512 * 2);
  u16* nhat_t = (u16*)take(2048L * 512 * 2);
  // B region: qkv -> sctx/tctx/tmean/hbuf
  u16* q_s  = (u16*)take(16384L * 512 * 2);
  u16* kv_s = (u16*)take(2048L * 1024 * 2);
  u16* q_t  = (u16*)take(2048L * 512 * 2);
  u16* kv_t = (u16*)take(16384L * 1024 * 2);
  // S region: 23068672 B total
  char* Sreg = (char*)take(16777216 + 2097152 + 4194304);
  const size_t NEED = off;

  if (ws_size < NEED) {
    pz_diag<<<2048, 256, 0, stream>>>(out, (long)out_size, (float)(ws_size >> 20));
    return;
  }

  u16* wtT  = (u16*)Sreg;
  u16* wpb  = (u16*)(Sreg + 524288);
  u16* Sb   = (u16*)Sreg;
  u16* vt_s = (u16*)(Sreg + 16777216);          // spatial V^T (2MB)
  u16* vtc  = (u16*)(Sreg + 16777216 + 2097152);// temporal V^T (4MB)
  float* pvs_sp = (float*)vtc;                  // spatial PV scratch (4MB, vtc idle)
  float* pvs_t  = (float*)vt_s;                 // temporal PV scratch (512KB, vt_s idle)
  u16* ctx_s = nhat_s;
  u16* ctx_t = nhat_t;
  u16* sctx  = q_s;
  u16* tctx  = kv_s;
  float* tmean = (float*)q_t;
  u16* hbuf  = kv_t;
  u16* gchunk = (u16*)Sreg;                     // 4096*2816*2 = 23068672 = full Sreg
  u16* winb   = (u16*)nhat_s;                   // 11.18MB in dead ctx_s region

  auto gemm = [&](const u16* A, const u16* B, const float* bias,
                  const u16* residB, const float* residF, u16* Cb, float* Cf,
                  int M, int N, int K, int ldA, int ldB, int ldC, int ldR,
                  long aSH, long bSH, long cSH, long rSH, int Z, float alpha) {
    dim3 g((N + 127) / 128, M / 128, Z);
    pz_gemm_bt<<<g, dim3(256), 0, stream>>>(A, B, bias, residB, residF, Cb, Cf,
        M, N, K, ldA, ldB, ldC, ldR, aSH, bSH, cSH, rSH, alpha);
  };

  // --- precompute ---
  pz_fold_qkv<<<3072, 256, 0, stream>>>(s_Wqkv, t_Wqkv, s_bqkv, t_bqkv,
      s_qg, s_qb, s_kg, s_kb, t_qg, t_qb, t_kg, t_kb, wq_s, wq_t, bqs, bqt);
  pz_transpose_f2b<<<dim3(8, 1, 8), 256, 0, stream>>>(s_Wo, wtT, 512, 512);
  pz_f2b<<<1024, 256, 0, stream>>>(s_Wp, wpb, 512 * 512);
  gemm(wpb, wtT, nullptr, nullptr, nullptr, wc_s, nullptr,
       512, 512, 512, 512, 512, 512, 0, 0, 0, 0, 0, 1, 1.0f);
  pz_transpose_f2b<<<dim3(8, 1, 8), 256, 0, stream>>>(t_Wo, wtT, 512, 512);
  pz_f2b<<<1024, 256, 0, stream>>>(t_Wp, wpb, 512 * 512);
  gemm(wpb, wtT, nullptr, nullptr, nullptr, wc_t, nullptr,
       512, 512, 512, 512, 512, 512, 0, 0, 0, 0, 0, 1, 1.0f);
  pz_fold_bc<<<1024, 256, 0, stream>>>(s_Wp, s_bo, s_bp, t_Wp, t_bo, t_bp, bcs, bct);
  pz_pad_wout<<<5632, 256, 0, stream>>>(mix_Wout, woutp);

  // --- LN ---
  pz_ln<<<16384, 256, 0, stream>>>(spat, nhat_s);
  pz_ln<<<2048, 256, 0, stream>>>(temp, nhat_t);

  // --- QKV projections ---
  gemm(nhat_s, wq_s,           bqs,       nullptr, nullptr, q_s,  nullptr,
       16384, 512,  512, 512, 512, 512,  0, 0,0,0,0, 1, 1.0f);
  gemm(nhat_t, wq_s + 512*512, bqs + 512, nullptr, nullptr, kv_s, nullptr,
       2048,  1024, 512, 512, 512, 1024, 0, 0,0,0,0, 1, 1.0f);
  gemm(nhat_t, wq_t,           bqt,       nullptr, nullptr, q_t,  nullptr,
       2048,  512,  512, 512, 512, 512,  0, 0,0,0,0, 1, 1.0f);
  gemm(nhat_s, wq_t + 512*512, bqt + 512, nullptr, nullptr, kv_t, nullptr,
       16384, 1024, 512, 512, 512, 1024, 0, 0,0,0,0, 1, 1.0f);

  // --- spatial-query attention (chunk: batch x 4 heads; S chunk = 16MB) ---
  for (int b = 0; b < 4; ++b)
    pz_transpose<<<dim3(8, 1, 8), 256, 0, stream>>>(kv_s + (long)b * 512 * 1024,
        vt_s + (long)b * 8 * 64 * 512, 512, 1024, 512);
  for (int b = 0; b < 4; ++b)
    for (int hc = 0; hc < 2; ++hc) {
      const u16* Aq = q_s + (long)b * 4096 * 512 + hc * 256;
      const u16* Bk = kv_s + (long)b * 512 * 1024 + hc * 256;
      gemm(Aq, Bk, nullptr, nullptr, nullptr, Sb, nullptr,
           4096, 512, 64, 512, 1024, 512, 0, 64, 64, 4096L * 512, 0, 4, 0.125f);
      pz_softmax<512><<<16384, 256, 0, stream>>>(Sb);
      const u16* Bv = vt_s + ((long)b * 8 + hc * 4) * 64 * 512;
      (void)hipMemsetAsync(pvs_sp, 0, 4L * 4096 * 64 * 4, stream);
      pz_gemm_pv<<<dim3(4, 32, 4), 256, 0, stream>>>(Sb, Bv, pvs_sp,
           4096, 512, 512, 4096L * 512, 64L * 512, 4096L * 64, 128);
      pz_pv_fin<<<4096, 256, 0, stream>>>(pvs_sp,
           ctx_s + (long)b * 4096 * 512 + hc * 256, 4096, 512);
    }

  // --- temporal-query attention (chunk: batch x 4-head group; S chunk = 16MB) ---
  for (int b = 0; b < 4; ++b) {
    const u16* Bk = kv_t + (long)b * 4096 * 1024;
    pz_transpose<<<dim3(64, 1, 8), 256, 0, stream>>>(Bk, vtc, 4096, 1024, 512);
    for (int hq = 0; hq < 2; ++hq) {
      const u16* Aq = q_t + (long)b * 512 * 512 + hq * 256;
      gemm(Aq, Bk + hq * 256, nullptr, nullptr, nullptr, Sb, nullptr,
           512, 4096, 64, 512, 1024, 4096, 0, 64, 64, 512L * 4096, 0, 4, 0.125f);
      pz_softmax<4096><<<2048, 256, 0, stream>>>(Sb);
      (void)hipMemsetAsync(pvs_t, 0, 4L * 512 * 64 * 4, stream);
      pz_gemm_pv<<<dim3(16, 4, 4), 256, 0, stream>>>(Sb, vtc + (long)hq * 4 * 64 * 4096,
           pvs_t, 512, 4096, 4096, 512L * 4096, 64L * 4096, 512L * 64, 256);
      pz_pv_fin<<<512, 256, 0, stream>>>(pvs_t,
           ctx_t + (long)b * 512 * 512 + hq * 256, 512, 512);
    }
  }

  // --- combined output projection (Wc = Wp.Wo) + f32 residual -> bf16 ctx ---
  gemm(ctx_s, wc_s, bcs, nullptr, spat, sctx, nullptr,
       16384, 512, 512, 512, 512, 512, 512, 0,0,0,0, 1, 1.0f);
  gemm(ctx_t, wc_t, bct, nullptr, temp, tctx, nullptr,
       2048,  512, 512, 512, 512, 512, 512, 0,0,0,0, 1, 1.0f);

  // --- t_mean + mix LN ---
  (void)hipMemsetAsync(tmean, 0, 4L * 512 * sizeof(float), stream);
  pz_tmean<<<dim3(16, 4), 256, 0, stream>>>(tctx, tmean);
  pz_mix_ln<<<16384, 256, 0, stream>>>(sctx, tmean, mix_g, mix_b, hbuf);

  // --- mix_Win -> bf16 (ctx_s region dead now) ---
  pz_f2b<<<21840, 256, 0, stream>>>(mix_Win, winb, 5460 * 1024);
  // --- out = mix_bout + sctx (split-K accumulates on top) ---
  pz_out_init<<<32768, 256, 0, stream>>>(mix_bout, sctx, out);

  // --- mix MLP in 4 row-chunks of 4096: fused u/v+gate, then split-K Wout ---
  for (int c = 0; c < 4; ++c) {
    const u16* Ah = hbuf + (long)c * 4096 * 1024;
    pz_gemm_uvgate<<<dim3(22, 32), 256, 0, stream>>>(Ah, winb, winb + 2730L * 1024,
        mix_bin, mix_bin + 2730, gchunk, 4096, 2730, 1024, 1024, 1024, 2816, 2816);
    pz_gemm_sk<<<dim3(4, 32, 4), 256, 0, stream>>>(gchunk, woutp,
        out + (long)c * 4096 * 512, 4096, 512, 2816, 2816, 512, 704);
  }
}